// Round 1
// baseline (4640.772 us; speedup 1.0000x reference)
//
#include <hip/hip_runtime.h>

// Problem constants (from reference): N=50000 nodes, E=600000 edges, D=128,
// L=4 layers, G=128 graphs.
#define NN 50000
#define NE 600000
#define DIM 128
#define NLAYER 4
#define NGRAPH 128

// ---------------- degree / normalization (edge-structure only, once) --------

__global__ void deg_kernel(const int* __restrict__ dst, float* __restrict__ deg, int e_cnt) {
    int e = blockIdx.x * blockDim.x + threadIdx.x;
    if (e < e_cnt) atomicAdd(&deg[dst[e]], 1.0f);
}

__global__ void dinv_kernel(float* __restrict__ deg, int n) {
    int i = blockIdx.x * blockDim.x + threadIdx.x;
    if (i < n) deg[i] = rsqrtf(deg[i] + 1.0f);  // +1 self-loop
}

__global__ void coef_kernel(const int* __restrict__ src, const int* __restrict__ dst,
                            const float* __restrict__ dinv, float* __restrict__ coef, int e_cnt) {
    int e = blockIdx.x * blockDim.x + threadIdx.x;
    if (e < e_cnt) coef[e] = dinv[src[e]] * dinv[dst[e]];
}

// ---------------- GEMM: H[N,128] = X[N,128] @ W[128,128] (fp32) -------------
// Block: 256 threads, 64 rows. W fully staged in LDS (64KB), X tile in LDS
// (32KB). Each thread: 8 rows x 4 cols register tile.

__launch_bounds__(256)
__global__ void gemm_kernel(const float* __restrict__ X, const float* __restrict__ Wl,
                            float* __restrict__ H, int nrows) {
    __shared__ float ws[DIM * DIM];   // 64 KB
    __shared__ float xs[64 * DIM];    // 32 KB
    const int tid = threadIdx.x;
    const int row0 = blockIdx.x * 64;

    // stage W (coalesced float4)
    for (int i = tid; i < DIM * DIM / 4; i += 256)
        ((float4*)ws)[i] = ((const float4*)Wl)[i];
    // stage X tile
    const int nr = min(64, nrows - row0);
    for (int i = tid; i < 64 * DIM / 4; i += 256) {
        int r = i >> 5;  // 32 float4 per row
        float4 v = make_float4(0.f, 0.f, 0.f, 0.f);
        if (r < nr) v = ((const float4*)(X + (size_t)row0 * DIM))[i];
        ((float4*)xs)[i] = v;
    }
    __syncthreads();

    const int rg = tid >> 5;        // 0..7  -> rows rg*8..rg*8+7
    const int cg = tid & 31;        // 0..31 -> cols cg*4..cg*4+3
    const int rbase = rg * 8;
    const int c = cg * 4;

    float acc[8][4];
    #pragma unroll
    for (int i = 0; i < 8; ++i)
        #pragma unroll
        for (int j = 0; j < 4; ++j) acc[i][j] = 0.f;

    #pragma unroll 4
    for (int k = 0; k < DIM; k += 4) {
        float4 w0 = *(float4*)&ws[(k + 0) * DIM + c];
        float4 w1 = *(float4*)&ws[(k + 1) * DIM + c];
        float4 w2 = *(float4*)&ws[(k + 2) * DIM + c];
        float4 w3 = *(float4*)&ws[(k + 3) * DIM + c];
        #pragma unroll
        for (int rr = 0; rr < 8; ++rr) {
            float4 xv = *(float4*)&xs[(rbase + rr) * DIM + k];
            acc[rr][0] += xv.x * w0.x + xv.y * w1.x + xv.z * w2.x + xv.w * w3.x;
            acc[rr][1] += xv.x * w0.y + xv.y * w1.y + xv.z * w2.y + xv.w * w3.y;
            acc[rr][2] += xv.x * w0.z + xv.y * w1.z + xv.z * w2.z + xv.w * w3.z;
            acc[rr][3] += xv.x * w0.w + xv.y * w1.w + xv.z * w2.w + xv.w * w3.w;
        }
    }

    #pragma unroll
    for (int rr = 0; rr < 8; ++rr) {
        int r = rbase + rr;
        if (row0 + r < nrows)
            *(float4*)&H[(size_t)(row0 + r) * DIM + c] =
                make_float4(acc[rr][0], acc[rr][1], acc[rr][2], acc[rr][3]);
    }
}

// ---------------- acc = x + h*dinv^2 + b[l] ---------------------------------

__global__ void init_acc_kernel(const float* __restrict__ xcur, const float* __restrict__ h,
                                const float* __restrict__ dinv, const float* __restrict__ bl,
                                float* __restrict__ acc) {
    int t = blockIdx.x * blockDim.x + threadIdx.x;   // one float4 per thread
    if (t >= NN * 32) return;
    int node = t >> 5;
    int c4 = t & 31;
    float d = dinv[node];
    float d2 = d * d;
    float4 xv = ((const float4*)xcur)[t];
    float4 hv = ((const float4*)h)[t];
    float4 bv = ((const float4*)bl)[c4];
    float4 r;
    r.x = xv.x + hv.x * d2 + bv.x;
    r.y = xv.y + hv.y * d2 + bv.y;
    r.z = xv.z + hv.z * d2 + bv.z;
    r.w = xv.w + hv.w * d2 + bv.w;
    ((float4*)acc)[t] = r;
}

// ---------------- edge scatter: acc[dst] += h[src] * coef -------------------
// 32 threads per edge, each owns one float4 chunk of the 128-dim row.

__global__ void scatter_kernel(const int* __restrict__ src, const int* __restrict__ dst,
                               const float* __restrict__ coef, const float* __restrict__ h,
                               float* __restrict__ acc) {
    int t = blockIdx.x * blockDim.x + threadIdx.x;
    if (t >= NE * 32) return;
    int e = t >> 5;
    int c4 = t & 31;
    int s = src[e];
    int d = dst[e];
    float cf = coef[e];
    float4 hv = ((const float4*)(h + (size_t)s * DIM))[c4];
    float* ap = acc + (size_t)d * DIM + c4 * 4;
    atomicAdd(ap + 0, hv.x * cf);
    atomicAdd(ap + 1, hv.y * cf);
    atomicAdd(ap + 2, hv.z * cf);
    atomicAdd(ap + 3, hv.w * cf);
}

// ---------------- LayerNorm + ReLU (wave per row) ---------------------------

__launch_bounds__(256)
__global__ void ln_relu_kernel(const float* __restrict__ acc, const float* __restrict__ gamma,
                               const float* __restrict__ beta, float* __restrict__ xout, int n) {
    int gt = blockIdx.x * blockDim.x + threadIdx.x;
    int row = gt >> 6;
    if (row >= n) return;
    int lane = threadIdx.x & 63;
    float2 v = ((const float2*)(acc + (size_t)row * DIM))[lane];
    float s = v.x + v.y;
    float sq = v.x * v.x + v.y * v.y;
    #pragma unroll
    for (int o = 32; o > 0; o >>= 1) {
        s += __shfl_xor(s, o);
        sq += __shfl_xor(sq, o);
    }
    float mean = s * (1.0f / DIM);
    float var = sq * (1.0f / DIM) - mean * mean;
    float rstd = rsqrtf(var + 1e-5f);
    float2 g = ((const float2*)gamma)[lane];
    float2 bt = ((const float2*)beta)[lane];
    float2 o;
    o.x = fmaxf((v.x - mean) * rstd * g.x + bt.x, 0.f);
    o.y = fmaxf((v.y - mean) * rstd * g.y + bt.y, 0.f);
    ((float2*)(xout + (size_t)row * DIM))[lane] = o;
}

// ---------------- global mean pool ------------------------------------------

__global__ void pool_kernel(const float* __restrict__ x, const int* __restrict__ batch,
                            float* __restrict__ out) {
    int t = blockIdx.x * blockDim.x + threadIdx.x;
    int node = t >> 6;
    if (node >= NN) return;
    int lane = t & 63;
    int g = batch[node];
    float2 v = ((const float2*)(x + (size_t)node * DIM))[lane];
    atomicAdd(&out[g * DIM + lane * 2 + 0], v.x);
    atomicAdd(&out[g * DIM + lane * 2 + 1], v.y);
}

__global__ void cnt_kernel(const int* __restrict__ batch, float* __restrict__ cnt) {
    int i = blockIdx.x * blockDim.x + threadIdx.x;
    if (i < NN) atomicAdd(&cnt[batch[i]], 1.0f);
}

__global__ void div_kernel(float* __restrict__ out, const float* __restrict__ cnt) {
    int t = blockIdx.x * blockDim.x + threadIdx.x;
    if (t >= NGRAPH * DIM) return;
    int g = t >> 7;  // /DIM
    out[t] /= fmaxf(cnt[g], 1.0f);
}

// ---------------- launch ----------------------------------------------------

extern "C" void kernel_launch(void* const* d_in, const int* in_sizes, int n_in,
                              void* d_out, int out_size, void* d_ws, size_t ws_size,
                              hipStream_t stream) {
    const float* x     = (const float*)d_in[0];
    const int*   ei    = (const int*)d_in[1];
    const int*   batch = (const int*)d_in[2];
    const float* W     = (const float*)d_in[3];
    const float* b     = (const float*)d_in[4];
    const float* gamma = (const float*)d_in[5];
    const float* beta  = (const float*)d_in[6];
    float* out = (float*)d_out;

    const int* srcE = ei;        // edge_index[0]
    const int* dstE = ei + NE;   // edge_index[1]

    // workspace layout (floats): xcur | h | acc | dinv | coef | cnt  (~79.4 MB)
    float* wsf  = (float*)d_ws;
    float* xcur = wsf;
    float* h    = xcur + (size_t)NN * DIM;
    float* acc  = h + (size_t)NN * DIM;
    float* dinv = acc + (size_t)NN * DIM;
    float* coef = dinv + NN;
    float* cnt  = coef + NE;

    // edge-structure preprocessing (shared by all 4 layers)
    hipMemsetAsync(dinv, 0, NN * sizeof(float), stream);
    deg_kernel<<<(NE + 255) / 256, 256, 0, stream>>>(dstE, dinv, NE);
    dinv_kernel<<<(NN + 255) / 256, 256, 0, stream>>>(dinv, NN);
    coef_kernel<<<(NE + 255) / 256, 256, 0, stream>>>(srcE, dstE, dinv, coef, NE);
    hipMemcpyAsync(xcur, x, (size_t)NN * DIM * sizeof(float), hipMemcpyDeviceToDevice, stream);

    for (int l = 0; l < NLAYER; ++l) {
        gemm_kernel<<<(NN + 63) / 64, 256, 0, stream>>>(xcur, W + (size_t)l * DIM * DIM, h, NN);
        init_acc_kernel<<<(NN * 32 + 255) / 256, 256, 0, stream>>>(xcur, h, dinv, b + l * DIM, acc);
        scatter_kernel<<<(NE * 32 + 255) / 256, 256, 0, stream>>>(srcE, dstE, coef, h, acc);
        ln_relu_kernel<<<(NN * 64 + 255) / 256, 256, 0, stream>>>(
            acc, gamma + l * DIM, beta + l * DIM, xcur, NN);
    }

    hipMemsetAsync(out, 0, (size_t)NGRAPH * DIM * sizeof(float), stream);
    hipMemsetAsync(cnt, 0, NGRAPH * sizeof(float), stream);
    pool_kernel<<<(NN * 64 + 255) / 256, 256, 0, stream>>>(xcur, batch, out);
    cnt_kernel<<<(NN + 255) / 256, 256, 0, stream>>>(batch, cnt);
    div_kernel<<<(NGRAPH * DIM + 255) / 256, 256, 0, stream>>>(out, cnt);
}

// Round 2
// 931.755 us; speedup vs baseline: 4.9807x; 4.9807x over previous
//
#include <hip/hip_runtime.h>

// N=50000 nodes, E=600000 edges, D=128, L=4 layers, G=128 graphs.
#define NN 50000
#define NE 600000
#define DIM 128
#define NLAYER 4
#define NGRAPH 128

// ---------------- CSR build (edge structure only, once per launch) ----------

__global__ void deg_kernel(const int* __restrict__ dst, int* __restrict__ deg) {
    int e = blockIdx.x * blockDim.x + threadIdx.x;
    if (e < NE) atomicAdd(&deg[dst[e]], 1);
}

// single-block exclusive scan over deg[NN] -> row_ptr[NN+1]
__launch_bounds__(256)
__global__ void scan_kernel(const int* __restrict__ deg, int* __restrict__ row_ptr) {
    __shared__ int lsum[256];
    const int tid = threadIdx.x;
    const int STRIP = (NN + 255) / 256;  // 196
    const int beg = tid * STRIP;
    const int end = min(beg + STRIP, NN);
    int s = 0;
    for (int i = beg; i < end; ++i) s += deg[i];
    lsum[tid] = s;
    __syncthreads();
    for (int o = 1; o < 256; o <<= 1) {
        int t = 0;
        if (tid >= o) t = lsum[tid - o];
        __syncthreads();
        lsum[tid] += t;
        __syncthreads();
    }
    int running = lsum[tid] - s;  // exclusive prefix
    for (int i = beg; i < end; ++i) {
        row_ptr[i] = running;
        running += deg[i];
    }
    if (tid == 255) row_ptr[NN] = running;
}

__global__ void dinv_kernel(const int* __restrict__ deg, float* __restrict__ dinv) {
    int i = blockIdx.x * blockDim.x + threadIdx.x;
    if (i < NN) dinv[i] = rsqrtf((float)deg[i] + 1.0f);  // +1 self-loop
}

__global__ void fill_kernel(const int* __restrict__ src, const int* __restrict__ dst,
                            const int* __restrict__ row_ptr, int* __restrict__ cnt,
                            int* __restrict__ csr_src) {
    int e = blockIdx.x * blockDim.x + threadIdx.x;
    if (e >= NE) return;
    int d = dst[e];
    int pos = row_ptr[d] + atomicAdd(&cnt[d], 1);
    csr_src[pos] = src[e];
}

// ---------------- GEMM: H2[N,128] = (X[N,128] @ W[128,128]) * dinv[row] -----

__launch_bounds__(256)
__global__ void gemm_kernel(const float* __restrict__ X, const float* __restrict__ Wl,
                            const float* __restrict__ dinv, float* __restrict__ H2, int nrows) {
    __shared__ float ws[DIM * DIM];   // 64 KB
    __shared__ float xs[64 * DIM];    // 32 KB
    const int tid = threadIdx.x;
    const int row0 = blockIdx.x * 64;

    for (int i = tid; i < DIM * DIM / 4; i += 256)
        ((float4*)ws)[i] = ((const float4*)Wl)[i];
    const int nr = min(64, nrows - row0);
    for (int i = tid; i < 64 * DIM / 4; i += 256) {
        int r = i >> 5;
        float4 v = make_float4(0.f, 0.f, 0.f, 0.f);
        if (r < nr) v = ((const float4*)(X + (size_t)row0 * DIM))[i];
        ((float4*)xs)[i] = v;
    }
    __syncthreads();

    const int rg = tid >> 5;
    const int cg = tid & 31;
    const int rbase = rg * 8;
    const int c = cg * 4;

    float acc[8][4];
    #pragma unroll
    for (int i = 0; i < 8; ++i)
        #pragma unroll
        for (int j = 0; j < 4; ++j) acc[i][j] = 0.f;

    #pragma unroll 4
    for (int k = 0; k < DIM; k += 4) {
        float4 w0 = *(float4*)&ws[(k + 0) * DIM + c];
        float4 w1 = *(float4*)&ws[(k + 1) * DIM + c];
        float4 w2 = *(float4*)&ws[(k + 2) * DIM + c];
        float4 w3 = *(float4*)&ws[(k + 3) * DIM + c];
        #pragma unroll
        for (int rr = 0; rr < 8; ++rr) {
            float4 xv = *(float4*)&xs[(rbase + rr) * DIM + k];
            acc[rr][0] += xv.x * w0.x + xv.y * w1.x + xv.z * w2.x + xv.w * w3.x;
            acc[rr][1] += xv.x * w0.y + xv.y * w1.y + xv.z * w2.y + xv.w * w3.y;
            acc[rr][2] += xv.x * w0.z + xv.y * w1.z + xv.z * w2.z + xv.w * w3.z;
            acc[rr][3] += xv.x * w0.w + xv.y * w1.w + xv.z * w2.w + xv.w * w3.w;
        }
    }

    #pragma unroll
    for (int rr = 0; rr < 8; ++rr) {
        int r = row0 + rbase + rr;
        if (r < nrows) {
            float dv = dinv[r];
            *(float4*)&H2[(size_t)r * DIM + c] =
                make_float4(acc[rr][0] * dv, acc[rr][1] * dv, acc[rr][2] * dv, acc[rr][3] * dv);
        }
    }
}

// ---------------- fused gather + residual + bias + LayerNorm + ReLU ---------
// One wave (64 lanes) per destination node; lane owns a float2 chunk.
// acc = x[node] + b + dinv[node] * (h2[node] + sum_{e in CSR[node]} h2[src_e])

__launch_bounds__(256)
__global__ void gather_ln_kernel(const float* __restrict__ xcur, const float* __restrict__ h2,
                                 const float* __restrict__ dinv,
                                 const int* __restrict__ row_ptr, const int* __restrict__ csr_src,
                                 const float* __restrict__ bl, const float* __restrict__ gamma,
                                 const float* __restrict__ beta, float* __restrict__ xout) {
    int node = blockIdx.x * 4 + (threadIdx.x >> 6);
    if (node >= NN) return;
    int lane = threadIdx.x & 63;
    int beg = row_ptr[node];
    int end = row_ptr[node + 1];

    float2 s = ((const float2*)(h2 + (size_t)node * DIM))[lane];  // self-loop term
    for (int e = beg; e < end; ++e) {
        int sn = csr_src[e];
        float2 hv = ((const float2*)(h2 + (size_t)sn * DIM))[lane];
        s.x += hv.x;
        s.y += hv.y;
    }
    float dn = dinv[node];
    float2 xv = ((const float2*)(xcur + (size_t)node * DIM))[lane];
    float2 bv = ((const float2*)bl)[lane];
    float ax = xv.x + s.x * dn + bv.x;
    float ay = xv.y + s.y * dn + bv.y;

    float sum = ax + ay;
    float sq = ax * ax + ay * ay;
    #pragma unroll
    for (int o = 32; o > 0; o >>= 1) {
        sum += __shfl_xor(sum, o);
        sq += __shfl_xor(sq, o);
    }
    float mean = sum * (1.0f / DIM);
    float var = sq * (1.0f / DIM) - mean * mean;
    float rstd = rsqrtf(var + 1e-5f);
    float2 g = ((const float2*)gamma)[lane];
    float2 bt = ((const float2*)beta)[lane];
    float2 o;
    o.x = fmaxf((ax - mean) * rstd * g.x + bt.x, 0.f);
    o.y = fmaxf((ay - mean) * rstd * g.y + bt.y, 0.f);
    ((float2*)(xout + (size_t)node * DIM))[lane] = o;
}

// ---------------- global mean pool ------------------------------------------

__global__ void pool_kernel(const float* __restrict__ x, const int* __restrict__ batch,
                            float* __restrict__ out) {
    int t = blockIdx.x * blockDim.x + threadIdx.x;
    int node = t >> 6;
    if (node >= NN) return;
    int lane = t & 63;
    int g = batch[node];
    float2 v = ((const float2*)(x + (size_t)node * DIM))[lane];
    atomicAdd(&out[g * DIM + lane * 2 + 0], v.x);
    atomicAdd(&out[g * DIM + lane * 2 + 1], v.y);
}

__global__ void cnt_kernel(const int* __restrict__ batch, float* __restrict__ cnt) {
    int i = blockIdx.x * blockDim.x + threadIdx.x;
    if (i < NN) atomicAdd(&cnt[batch[i]], 1.0f);
}

__global__ void div_kernel(float* __restrict__ out, const float* __restrict__ cnt) {
    int t = blockIdx.x * blockDim.x + threadIdx.x;
    if (t >= NGRAPH * DIM) return;
    int g = t >> 7;
    out[t] /= fmaxf(cnt[g], 1.0f);
}

// ---------------- launch ----------------------------------------------------

extern "C" void kernel_launch(void* const* d_in, const int* in_sizes, int n_in,
                              void* d_out, int out_size, void* d_ws, size_t ws_size,
                              hipStream_t stream) {
    const float* x     = (const float*)d_in[0];
    const int*   ei    = (const int*)d_in[1];
    const int*   batch = (const int*)d_in[2];
    const float* W     = (const float*)d_in[3];
    const float* b     = (const float*)d_in[4];
    const float* gamma = (const float*)d_in[5];
    const float* beta  = (const float*)d_in[6];
    float* out = (float*)d_out;

    const int* srcE = ei;        // edge_index[0]
    const int* dstE = ei + NE;   // edge_index[1]

    // workspace layout
    char* p = (char*)d_ws;
    float* xA      = (float*)p;  p += (size_t)NN * DIM * sizeof(float);   // 25.6 MB
    float* h2      = (float*)p;  p += (size_t)NN * DIM * sizeof(float);   // 25.6 MB
    float* dinv    = (float*)p;  p += (size_t)NN * sizeof(float);
    int*   deg     = (int*)p;    p += (size_t)NN * sizeof(int);
    int*   ccnt    = (int*)p;    p += (size_t)NN * sizeof(int);
    int*   row_ptr = (int*)p;    p += (size_t)(NN + 1) * sizeof(int);
    int*   csr_src = (int*)p;    p += (size_t)NE * sizeof(int);
    float* gcnt    = (float*)p;  p += (size_t)NGRAPH * sizeof(float);

    // CSR build
    hipMemsetAsync(deg, 0, NN * sizeof(int), stream);
    hipMemsetAsync(ccnt, 0, NN * sizeof(int), stream);
    deg_kernel<<<(NE + 255) / 256, 256, 0, stream>>>(dstE, deg);
    scan_kernel<<<1, 256, 0, stream>>>(deg, row_ptr);
    dinv_kernel<<<(NN + 255) / 256, 256, 0, stream>>>(deg, dinv);
    fill_kernel<<<(NE + 255) / 256, 256, 0, stream>>>(srcE, dstE, row_ptr, ccnt, csr_src);

    const float* xin = x;
    for (int l = 0; l < NLAYER; ++l) {
        gemm_kernel<<<(NN + 63) / 64, 256, 0, stream>>>(xin, W + (size_t)l * DIM * DIM, dinv, h2, NN);
        gather_ln_kernel<<<(NN + 3) / 4, 256, 0, stream>>>(
            xin, h2, dinv, row_ptr, csr_src, b + l * DIM, gamma + l * DIM, beta + l * DIM, xA);
        xin = xA;  // in-place safe: each row read only by its own wave before write
    }

    hipMemsetAsync(out, 0, (size_t)NGRAPH * DIM * sizeof(float), stream);
    hipMemsetAsync(gcnt, 0, NGRAPH * sizeof(float), stream);
    pool_kernel<<<(NN * 64 + 255) / 256, 256, 0, stream>>>(xA, batch, out);
    cnt_kernel<<<(NN + 255) / 256, 256, 0, stream>>>(batch, gcnt);
    div_kernel<<<(NGRAPH * DIM + 255) / 256, 256, 0, stream>>>(out, gcnt);
}

// Round 3
// 749.370 us; speedup vs baseline: 6.1929x; 1.2434x over previous
//
#include <hip/hip_runtime.h>

// N=50000 nodes, E=600000 edges, D=128, L=4 layers, G=128 graphs.
#define NN 50000
#define NE 600000
#define DIM 128
#define NLAYER 4
#define NGRAPH 128

// ---------------- CSR build (edge structure only, once per launch) ----------

__global__ void deg_kernel(const int* __restrict__ dst, int* __restrict__ deg) {
    int e = blockIdx.x * blockDim.x + threadIdx.x;
    if (e < NE) atomicAdd(&deg[dst[e]], 1);
}

// single-block exclusive scan over deg[NN] -> row_ptr[NN+1]
__launch_bounds__(256)
__global__ void scan_kernel(const int* __restrict__ deg, int* __restrict__ row_ptr) {
    __shared__ int lsum[256];
    const int tid = threadIdx.x;
    const int STRIP = (NN + 255) / 256;  // 196
    const int beg = tid * STRIP;
    const int end = min(beg + STRIP, NN);
    int s = 0;
    for (int i = beg; i < end; ++i) s += deg[i];
    lsum[tid] = s;
    __syncthreads();
    for (int o = 1; o < 256; o <<= 1) {
        int t = 0;
        if (tid >= o) t = lsum[tid - o];
        __syncthreads();
        lsum[tid] += t;
        __syncthreads();
    }
    int running = lsum[tid] - s;  // exclusive prefix
    for (int i = beg; i < end; ++i) {
        row_ptr[i] = running;
        running += deg[i];
    }
    if (tid == 255) row_ptr[NN] = running;
}

__global__ void dinv_kernel(const int* __restrict__ deg, float* __restrict__ dinv) {
    int i = blockIdx.x * blockDim.x + threadIdx.x;
    if (i < NN) dinv[i] = rsqrtf((float)deg[i] + 1.0f);  // +1 self-loop
}

__global__ void fill_kernel(const int* __restrict__ src, const int* __restrict__ dst,
                            const int* __restrict__ row_ptr, int* __restrict__ cnt,
                            int* __restrict__ csr_src) {
    int e = blockIdx.x * blockDim.x + threadIdx.x;
    if (e >= NE) return;
    int d = dst[e];
    int pos = row_ptr[d] + atomicAdd(&cnt[d], 1);
    csr_src[pos] = src[e];
}

// ---------------- GEMM: H2[N,128] = (X[N,128] @ W[128,128]) * dinv[row] -----

__launch_bounds__(256)
__global__ void gemm_kernel(const float* __restrict__ X, const float* __restrict__ Wl,
                            const float* __restrict__ dinv, float* __restrict__ H2, int nrows) {
    __shared__ float ws[DIM * DIM];   // 64 KB
    __shared__ float xs[64 * DIM];    // 32 KB
    const int tid = threadIdx.x;
    const int row0 = blockIdx.x * 64;

    for (int i = tid; i < DIM * DIM / 4; i += 256)
        ((float4*)ws)[i] = ((const float4*)Wl)[i];
    const int nr = min(64, nrows - row0);
    for (int i = tid; i < 64 * DIM / 4; i += 256) {
        int r = i >> 5;
        float4 v = make_float4(0.f, 0.f, 0.f, 0.f);
        if (r < nr) v = ((const float4*)(X + (size_t)row0 * DIM))[i];
        ((float4*)xs)[i] = v;
    }
    __syncthreads();

    const int rg = tid >> 5;
    const int cg = tid & 31;
    const int rbase = rg * 8;
    const int c = cg * 4;

    float acc[8][4];
    #pragma unroll
    for (int i = 0; i < 8; ++i)
        #pragma unroll
        for (int j = 0; j < 4; ++j) acc[i][j] = 0.f;

    #pragma unroll 4
    for (int k = 0; k < DIM; k += 4) {
        float4 w0 = *(float4*)&ws[(k + 0) * DIM + c];
        float4 w1 = *(float4*)&ws[(k + 1) * DIM + c];
        float4 w2 = *(float4*)&ws[(k + 2) * DIM + c];
        float4 w3 = *(float4*)&ws[(k + 3) * DIM + c];
        #pragma unroll
        for (int rr = 0; rr < 8; ++rr) {
            float4 xv = *(float4*)&xs[(rbase + rr) * DIM + k];
            acc[rr][0] += xv.x * w0.x + xv.y * w1.x + xv.z * w2.x + xv.w * w3.x;
            acc[rr][1] += xv.x * w0.y + xv.y * w1.y + xv.z * w2.y + xv.w * w3.y;
            acc[rr][2] += xv.x * w0.z + xv.y * w1.z + xv.z * w2.z + xv.w * w3.z;
            acc[rr][3] += xv.x * w0.w + xv.y * w1.w + xv.z * w2.w + xv.w * w3.w;
        }
    }

    #pragma unroll
    for (int rr = 0; rr < 8; ++rr) {
        int r = row0 + rbase + rr;
        if (r < nrows) {
            float dv = dinv[r];
            *(float4*)&H2[(size_t)r * DIM + c] =
                make_float4(acc[rr][0] * dv, acc[rr][1] * dv, acc[rr][2] * dv, acc[rr][3] * dv);
        }
    }
}

// ---------------- fused gather + residual + bias + LayerNorm + ReLU ---------
// One wave (64 lanes) per destination node; lane owns a float2 chunk.
// acc = x[node] + b + dinv[node] * (h2[node] + sum_{e in CSR[node]} h2[src_e])

__launch_bounds__(256)
__global__ void gather_ln_kernel(const float* __restrict__ xcur, const float* __restrict__ h2,
                                 const float* __restrict__ dinv,
                                 const int* __restrict__ row_ptr, const int* __restrict__ csr_src,
                                 const float* __restrict__ bl, const float* __restrict__ gamma,
                                 const float* __restrict__ beta, float* __restrict__ xout) {
    int node = blockIdx.x * 4 + (threadIdx.x >> 6);
    if (node >= NN) return;
    int lane = threadIdx.x & 63;
    int beg = row_ptr[node];
    int end = row_ptr[node + 1];

    float2 s = ((const float2*)(h2 + (size_t)node * DIM))[lane];  // self-loop term
    for (int e = beg; e < end; ++e) {
        int sn = csr_src[e];
        float2 hv = ((const float2*)(h2 + (size_t)sn * DIM))[lane];
        s.x += hv.x;
        s.y += hv.y;
    }
    float dn = dinv[node];
    float2 xv = ((const float2*)(xcur + (size_t)node * DIM))[lane];
    float2 bv = ((const float2*)bl)[lane];
    float ax = xv.x + s.x * dn + bv.x;
    float ay = xv.y + s.y * dn + bv.y;

    float sum = ax + ay;
    float sq = ax * ax + ay * ay;
    #pragma unroll
    for (int o = 32; o > 0; o >>= 1) {
        sum += __shfl_xor(sum, o);
        sq += __shfl_xor(sq, o);
    }
    float mean = sum * (1.0f / DIM);
    float var = sq * (1.0f / DIM) - mean * mean;
    float rstd = rsqrtf(var + 1e-5f);
    float2 g = ((const float2*)gamma)[lane];
    float2 bt = ((const float2*)beta)[lane];
    float2 o;
    o.x = fmaxf((ax - mean) * rstd * g.x + bt.x, 0.f);
    o.y = fmaxf((ay - mean) * rstd * g.y + bt.y, 0.f);
    ((float2*)(xout + (size_t)node * DIM))[lane] = o;
}

// ---------------- global mean pool (batch is SORTED -> segments) ------------

// bounds[g] = lower_bound(batch, g), for g = 0..NGRAPH
__global__ void bounds_kernel(const int* __restrict__ batch, int* __restrict__ bounds) {
    int g = threadIdx.x;
    if (g > NGRAPH) return;
    int lo = 0, hi = NN;
    while (lo < hi) {
        int mid = (lo + hi) >> 1;
        if (batch[mid] < g) lo = mid + 1; else hi = mid;
    }
    bounds[g] = lo;
}

// one block per graph: sum rows [bounds[g], bounds[g+1]), divide, write out.
__launch_bounds__(256)
__global__ void pool_kernel(const float* __restrict__ x, const int* __restrict__ bounds,
                            float* __restrict__ out) {
    __shared__ float part[DIM];
    int g = blockIdx.x;
    int beg = bounds[g], end = bounds[g + 1];
    int half = threadIdx.x >> 7;   // 0 or 1
    int d = threadIdx.x & 127;
    float s = 0.f;
    for (int r = beg + half; r < end; r += 2)
        s += x[(size_t)r * DIM + d];
    if (half == 1) part[d] = s;
    __syncthreads();
    if (half == 0) {
        float tot = s + part[d];
        float cntf = (float)(end - beg);
        out[g * DIM + d] = tot / fmaxf(cntf, 1.0f);
    }
}

// ---------------- launch ----------------------------------------------------

extern "C" void kernel_launch(void* const* d_in, const int* in_sizes, int n_in,
                              void* d_out, int out_size, void* d_ws, size_t ws_size,
                              hipStream_t stream) {
    const float* x     = (const float*)d_in[0];
    const int*   ei    = (const int*)d_in[1];
    const int*   batch = (const int*)d_in[2];
    const float* W     = (const float*)d_in[3];
    const float* b     = (const float*)d_in[4];
    const float* gamma = (const float*)d_in[5];
    const float* beta  = (const float*)d_in[6];
    float* out = (float*)d_out;

    const int* srcE = ei;        // edge_index[0]
    const int* dstE = ei + NE;   // edge_index[1]

    // workspace layout
    char* p = (char*)d_ws;
    float* xA      = (float*)p;  p += (size_t)NN * DIM * sizeof(float);   // 25.6 MB
    float* h2      = (float*)p;  p += (size_t)NN * DIM * sizeof(float);   // 25.6 MB
    float* dinv    = (float*)p;  p += (size_t)NN * sizeof(float);
    int*   deg     = (int*)p;    p += (size_t)NN * sizeof(int);
    int*   ccnt    = (int*)p;    p += (size_t)NN * sizeof(int);
    int*   row_ptr = (int*)p;    p += (size_t)(NN + 1) * sizeof(int);
    int*   csr_src = (int*)p;    p += (size_t)NE * sizeof(int);
    int*   bounds  = (int*)p;    p += (size_t)(NGRAPH + 1) * sizeof(int);

    // CSR build
    hipMemsetAsync(deg, 0, NN * sizeof(int), stream);
    hipMemsetAsync(ccnt, 0, NN * sizeof(int), stream);
    deg_kernel<<<(NE + 255) / 256, 256, 0, stream>>>(dstE, deg);
    scan_kernel<<<1, 256, 0, stream>>>(deg, row_ptr);
    dinv_kernel<<<(NN + 255) / 256, 256, 0, stream>>>(deg, dinv);
    fill_kernel<<<(NE + 255) / 256, 256, 0, stream>>>(srcE, dstE, row_ptr, ccnt, csr_src);
    bounds_kernel<<<1, 256, 0, stream>>>(batch, bounds);

    const float* xin = x;
    for (int l = 0; l < NLAYER; ++l) {
        gemm_kernel<<<(NN + 63) / 64, 256, 0, stream>>>(xin, W + (size_t)l * DIM * DIM, dinv, h2, NN);
        gather_ln_kernel<<<(NN + 3) / 4, 256, 0, stream>>>(
            xin, h2, dinv, row_ptr, csr_src, b + l * DIM, gamma + l * DIM, beta + l * DIM, xA);
        xin = xA;  // in-place safe: each row read only by its own wave before write
    }

    pool_kernel<<<NGRAPH, 256, 0, stream>>>(xA, bounds, out);
}

// Round 4
// 670.983 us; speedup vs baseline: 6.9164x; 1.1168x over previous
//
#include <hip/hip_runtime.h>

// N=50000 nodes, E=600000 edges, D=128, L=4 layers, G=128 graphs.
#define NN 50000
#define NE 600000
#define DIM 128
#define NLAYER 4
#define NGRAPH 128
#define SCAN_BLOCKS ((NN + 255) / 256)   // 196

// ---------------- CSR build (edge structure only, once per launch) ----------

__global__ void deg_kernel(const int* __restrict__ dst, int* __restrict__ deg) {
    int e = blockIdx.x * blockDim.x + threadIdx.x;
    if (e < NE) atomicAdd(&deg[dst[e]], 1);
}

// stage 1: per-block (256-element) sums of deg
__launch_bounds__(256)
__global__ void blocksum_kernel(const int* __restrict__ deg, int* __restrict__ bsum) {
    int i = blockIdx.x * 256 + threadIdx.x;
    int v = (i < NN) ? deg[i] : 0;
    #pragma unroll
    for (int o = 32; o > 0; o >>= 1) v += __shfl_xor(v, o);
    __shared__ int ws[4];
    int wid = threadIdx.x >> 6;
    if ((threadIdx.x & 63) == 0) ws[wid] = v;
    __syncthreads();
    if (threadIdx.x == 0) bsum[blockIdx.x] = ws[0] + ws[1] + ws[2] + ws[3];
}

// stage 2: exclusive scan of the 196 block sums (single small block)
__launch_bounds__(256)
__global__ void scanb_kernel(int* __restrict__ bsum) {
    __shared__ int s[256];
    int tid = threadIdx.x;
    int v = (tid < SCAN_BLOCKS) ? bsum[tid] : 0;
    s[tid] = v;
    __syncthreads();
    for (int o = 1; o < 256; o <<= 1) {
        int t = (tid >= o) ? s[tid - o] : 0;
        __syncthreads();
        s[tid] += t;
        __syncthreads();
    }
    if (tid < SCAN_BLOCKS) bsum[tid] = s[tid] - v;  // exclusive
}

// stage 3: per-block Hillis-Steele scan + block offset -> row_ptr; fuse dinv.
__launch_bounds__(256)
__global__ void rowptr_kernel(const int* __restrict__ deg, const int* __restrict__ bsum,
                              int* __restrict__ row_ptr, float* __restrict__ dinv) {
    __shared__ int s[256];
    int tid = threadIdx.x;
    int i = blockIdx.x * 256 + tid;
    int d = (i < NN) ? deg[i] : 0;
    s[tid] = d;
    __syncthreads();
    for (int o = 1; o < 256; o <<= 1) {
        int t = (tid >= o) ? s[tid - o] : 0;
        __syncthreads();
        s[tid] += t;
        __syncthreads();
    }
    if (i < NN) {
        row_ptr[i] = bsum[blockIdx.x] + s[tid] - d;  // exclusive prefix
        dinv[i] = rsqrtf((float)d + 1.0f);           // +1 self-loop
    }
    if (i == 0) row_ptr[NN] = NE;  // total edges known by construction
}

__global__ void fill_kernel(const int* __restrict__ src, const int* __restrict__ dst,
                            const int* __restrict__ row_ptr, int* __restrict__ cnt,
                            int* __restrict__ csr_src) {
    int e = blockIdx.x * blockDim.x + threadIdx.x;
    if (e >= NE) return;
    int d = dst[e];
    int pos = row_ptr[d] + atomicAdd(&cnt[d], 1);
    csr_src[pos] = src[e];
}

// ---------------- GEMM: H2[N,128] = (X[N,128] @ W[128,128]) * dinv[row] -----

__launch_bounds__(256)
__global__ void gemm_kernel(const float* __restrict__ X, const float* __restrict__ Wl,
                            const float* __restrict__ dinv, float* __restrict__ H2, int nrows) {
    __shared__ float ws[DIM * DIM];   // 64 KB
    __shared__ float xs[64 * DIM];    // 32 KB
    const int tid = threadIdx.x;
    const int row0 = blockIdx.x * 64;

    for (int i = tid; i < DIM * DIM / 4; i += 256)
        ((float4*)ws)[i] = ((const float4*)Wl)[i];
    const int nr = min(64, nrows - row0);
    for (int i = tid; i < 64 * DIM / 4; i += 256) {
        int r = i >> 5;
        float4 v = make_float4(0.f, 0.f, 0.f, 0.f);
        if (r < nr) v = ((const float4*)(X + (size_t)row0 * DIM))[i];
        ((float4*)xs)[i] = v;
    }
    __syncthreads();

    const int rg = tid >> 5;
    const int cg = tid & 31;
    const int rbase = rg * 8;
    const int c = cg * 4;

    float acc[8][4];
    #pragma unroll
    for (int i = 0; i < 8; ++i)
        #pragma unroll
        for (int j = 0; j < 4; ++j) acc[i][j] = 0.f;

    #pragma unroll 4
    for (int k = 0; k < DIM; k += 4) {
        float4 w0 = *(float4*)&ws[(k + 0) * DIM + c];
        float4 w1 = *(float4*)&ws[(k + 1) * DIM + c];
        float4 w2 = *(float4*)&ws[(k + 2) * DIM + c];
        float4 w3 = *(float4*)&ws[(k + 3) * DIM + c];
        #pragma unroll
        for (int rr = 0; rr < 8; ++rr) {
            float4 xv = *(float4*)&xs[(rbase + rr) * DIM + k];
            acc[rr][0] += xv.x * w0.x + xv.y * w1.x + xv.z * w2.x + xv.w * w3.x;
            acc[rr][1] += xv.x * w0.y + xv.y * w1.y + xv.z * w2.y + xv.w * w3.y;
            acc[rr][2] += xv.x * w0.z + xv.y * w1.z + xv.z * w2.z + xv.w * w3.z;
            acc[rr][3] += xv.x * w0.w + xv.y * w1.w + xv.z * w2.w + xv.w * w3.w;
        }
    }

    #pragma unroll
    for (int rr = 0; rr < 8; ++rr) {
        int r = row0 + rbase + rr;
        if (r < nrows) {
            float dv = dinv[r];
            *(float4*)&H2[(size_t)r * DIM + c] =
                make_float4(acc[rr][0] * dv, acc[rr][1] * dv, acc[rr][2] * dv, acc[rr][3] * dv);
        }
    }
}

// ---------------- fused gather + residual + bias + LayerNorm + ReLU ---------
// One wave (64 lanes) per destination node; lane owns a float2 chunk.
// acc = x[node] + b + dinv[node] * (h2[node] + sum_{e in CSR[node]} h2[src_e])

__launch_bounds__(256)
__global__ void gather_ln_kernel(const float* __restrict__ xcur, const float* __restrict__ h2,
                                 const float* __restrict__ dinv,
                                 const int* __restrict__ row_ptr, const int* __restrict__ csr_src,
                                 const float* __restrict__ bl, const float* __restrict__ gamma,
                                 const float* __restrict__ beta, float* __restrict__ xout) {
    int node = blockIdx.x * 4 + (threadIdx.x >> 6);
    if (node >= NN) return;
    int lane = threadIdx.x & 63;
    int beg = row_ptr[node];
    int end = row_ptr[node + 1];

    float2 s = ((const float2*)(h2 + (size_t)node * DIM))[lane];  // self-loop term
    for (int e = beg; e < end; ++e) {
        int sn = csr_src[e];
        float2 hv = ((const float2*)(h2 + (size_t)sn * DIM))[lane];
        s.x += hv.x;
        s.y += hv.y;
    }
    float dn = dinv[node];
    float2 xv = ((const float2*)(xcur + (size_t)node * DIM))[lane];
    float2 bv = ((const float2*)bl)[lane];
    float ax = xv.x + s.x * dn + bv.x;
    float ay = xv.y + s.y * dn + bv.y;

    float sum = ax + ay;
    float sq = ax * ax + ay * ay;
    #pragma unroll
    for (int o = 32; o > 0; o >>= 1) {
        sum += __shfl_xor(sum, o);
        sq += __shfl_xor(sq, o);
    }
    float mean = sum * (1.0f / DIM);
    float var = sq * (1.0f / DIM) - mean * mean;
    float rstd = rsqrtf(var + 1e-5f);
    float2 g = ((const float2*)gamma)[lane];
    float2 bt = ((const float2*)beta)[lane];
    float2 o;
    o.x = fmaxf((ax - mean) * rstd * g.x + bt.x, 0.f);
    o.y = fmaxf((ay - mean) * rstd * g.y + bt.y, 0.f);
    ((float2*)(xout + (size_t)node * DIM))[lane] = o;
}

// ---------------- global mean pool (batch is SORTED -> segments) ------------

__global__ void bounds_kernel(const int* __restrict__ batch, int* __restrict__ bounds) {
    int g = threadIdx.x;
    if (g > NGRAPH) return;
    int lo = 0, hi = NN;
    while (lo < hi) {
        int mid = (lo + hi) >> 1;
        if (batch[mid] < g) lo = mid + 1; else hi = mid;
    }
    bounds[g] = lo;
}

__launch_bounds__(256)
__global__ void pool_kernel(const float* __restrict__ x, const int* __restrict__ bounds,
                            float* __restrict__ out) {
    __shared__ float part[DIM];
    int g = blockIdx.x;
    int beg = bounds[g], end = bounds[g + 1];
    int half = threadIdx.x >> 7;   // 0 or 1
    int d = threadIdx.x & 127;
    float s = 0.f;
    for (int r = beg + half; r < end; r += 2)
        s += x[(size_t)r * DIM + d];
    if (half == 1) part[d] = s;
    __syncthreads();
    if (half == 0) {
        float tot = s + part[d];
        float cntf = (float)(end - beg);
        out[g * DIM + d] = tot / fmaxf(cntf, 1.0f);
    }
}

// ---------------- launch ----------------------------------------------------

extern "C" void kernel_launch(void* const* d_in, const int* in_sizes, int n_in,
                              void* d_out, int out_size, void* d_ws, size_t ws_size,
                              hipStream_t stream) {
    const float* x     = (const float*)d_in[0];
    const int*   ei    = (const int*)d_in[1];
    const int*   batch = (const int*)d_in[2];
    const float* W     = (const float*)d_in[3];
    const float* b     = (const float*)d_in[4];
    const float* gamma = (const float*)d_in[5];
    const float* beta  = (const float*)d_in[6];
    float* out = (float*)d_out;

    const int* srcE = ei;        // edge_index[0]
    const int* dstE = ei + NE;   // edge_index[1]

    // workspace layout
    char* p = (char*)d_ws;
    float* xA      = (float*)p;  p += (size_t)NN * DIM * sizeof(float);   // 25.6 MB
    float* h2      = (float*)p;  p += (size_t)NN * DIM * sizeof(float);   // 25.6 MB
    float* dinv    = (float*)p;  p += (size_t)NN * sizeof(float);
    int*   deg     = (int*)p;    p += (size_t)NN * sizeof(int);
    int*   ccnt    = (int*)p;    p += (size_t)NN * sizeof(int);
    int*   row_ptr = (int*)p;    p += (size_t)(NN + 1) * sizeof(int);
    int*   csr_src = (int*)p;    p += (size_t)NE * sizeof(int);
    int*   bounds  = (int*)p;    p += (size_t)(NGRAPH + 1) * sizeof(int);
    int*   bsum    = (int*)p;    p += (size_t)SCAN_BLOCKS * sizeof(int);

    // CSR build
    hipMemsetAsync(deg, 0, NN * sizeof(int), stream);
    hipMemsetAsync(ccnt, 0, NN * sizeof(int), stream);
    deg_kernel<<<(NE + 255) / 256, 256, 0, stream>>>(dstE, deg);
    blocksum_kernel<<<SCAN_BLOCKS, 256, 0, stream>>>(deg, bsum);
    scanb_kernel<<<1, 256, 0, stream>>>(bsum);
    rowptr_kernel<<<SCAN_BLOCKS, 256, 0, stream>>>(deg, bsum, row_ptr, dinv);
    fill_kernel<<<(NE + 255) / 256, 256, 0, stream>>>(srcE, dstE, row_ptr, ccnt, csr_src);
    bounds_kernel<<<1, 256, 0, stream>>>(batch, bounds);

    const float* xin = x;
    for (int l = 0; l < NLAYER; ++l) {
        gemm_kernel<<<(NN + 63) / 64, 256, 0, stream>>>(xin, W + (size_t)l * DIM * DIM, dinv, h2, NN);
        gather_ln_kernel<<<(NN + 3) / 4, 256, 0, stream>>>(
            xin, h2, dinv, row_ptr, csr_src, b + l * DIM, gamma + l * DIM, beta + l * DIM, xA);
        xin = xA;  // in-place safe: each row read only by its own wave before write
    }

    pool_kernel<<<NGRAPH, 256, 0, stream>>>(xA, bounds, out);
}

// Round 5
// 567.611 us; speedup vs baseline: 8.1760x; 1.1821x over previous
//
#include <hip/hip_runtime.h>

// N=50000 nodes, E=600000 edges, D=128, L=4 layers, G=128 graphs.
#define NN 50000
#define NE 600000
#define DIM 128
#define NLAYER 4
#define NGRAPH 128
#define SCAN_BLOCKS ((NN + 255) / 256)   // 196

typedef unsigned int u32;

// pack two fp32 -> 2x bf16 (round-to-nearest-even)
__device__ __forceinline__ u32 bf2(float a, float b) {
    u32 ua = __float_as_uint(a);
    ua = (ua + 0x7fffu + ((ua >> 16) & 1u)) >> 16;
    u32 ub = __float_as_uint(b);
    ub = (ub + 0x7fffu + ((ub >> 16) & 1u)) >> 16;
    return ua | (ub << 16);
}
__device__ __forceinline__ float bflo(u32 v) { return __uint_as_float(v << 16); }
__device__ __forceinline__ float bfhi(u32 v) { return __uint_as_float(v & 0xffff0000u); }

// ---------------- CSR build (edge structure only, once per launch) ----------

__global__ void deg_kernel(const int* __restrict__ dst, int* __restrict__ deg) {
    int e = blockIdx.x * blockDim.x + threadIdx.x;
    if (e < NE) atomicAdd(&deg[dst[e]], 1);
}

__launch_bounds__(256)
__global__ void blocksum_kernel(const int* __restrict__ deg, int* __restrict__ bsum) {
    int i = blockIdx.x * 256 + threadIdx.x;
    int v = (i < NN) ? deg[i] : 0;
    #pragma unroll
    for (int o = 32; o > 0; o >>= 1) v += __shfl_xor(v, o);
    __shared__ int ws[4];
    int wid = threadIdx.x >> 6;
    if ((threadIdx.x & 63) == 0) ws[wid] = v;
    __syncthreads();
    if (threadIdx.x == 0) bsum[blockIdx.x] = ws[0] + ws[1] + ws[2] + ws[3];
}

__launch_bounds__(256)
__global__ void scanb_kernel(int* __restrict__ bsum) {
    __shared__ int s[256];
    int tid = threadIdx.x;
    int v = (tid < SCAN_BLOCKS) ? bsum[tid] : 0;
    s[tid] = v;
    __syncthreads();
    for (int o = 1; o < 256; o <<= 1) {
        int t = (tid >= o) ? s[tid - o] : 0;
        __syncthreads();
        s[tid] += t;
        __syncthreads();
    }
    if (tid < SCAN_BLOCKS) bsum[tid] = s[tid] - v;  // exclusive
}

__launch_bounds__(256)
__global__ void rowptr_kernel(const int* __restrict__ deg, const int* __restrict__ bsum,
                              int* __restrict__ row_ptr, float* __restrict__ dinv) {
    __shared__ int s[256];
    int tid = threadIdx.x;
    int i = blockIdx.x * 256 + tid;
    int d = (i < NN) ? deg[i] : 0;
    s[tid] = d;
    __syncthreads();
    for (int o = 1; o < 256; o <<= 1) {
        int t = (tid >= o) ? s[tid - o] : 0;
        __syncthreads();
        s[tid] += t;
        __syncthreads();
    }
    if (i < NN) {
        row_ptr[i] = bsum[blockIdx.x] + s[tid] - d;  // exclusive prefix
        dinv[i] = rsqrtf((float)d + 1.0f);           // +1 self-loop
    }
    if (i == 0) row_ptr[NN] = NE;
}

__global__ void fill_kernel(const int* __restrict__ src, const int* __restrict__ dst,
                            const int* __restrict__ row_ptr, int* __restrict__ cnt,
                            int* __restrict__ csr_src) {
    int e = blockIdx.x * blockDim.x + threadIdx.x;
    if (e >= NE) return;
    int d = dst[e];
    int pos = row_ptr[d] + atomicAdd(&cnt[d], 1);
    csr_src[pos] = src[e];
}

// ---------------- GEMM: H2b[N,128](bf16) = (X @ W) * dinv[row] --------------
// 256 threads, 64-row tile. X tile in LDS (32 KB); W staged in 16-row slabs,
// double-buffered (2x8 KB). Total LDS 48 KB -> 3 blocks/CU.

__launch_bounds__(256)
__global__ void gemm_kernel(const float* __restrict__ X, const float* __restrict__ Wl,
                            const float* __restrict__ dinv, u32* __restrict__ H2b, int nrows) {
    __shared__ float xs[64 * DIM];        // 32 KB
    __shared__ float wsl[2][16 * DIM];    // 2 x 8 KB
    const int tid = threadIdx.x;
    const int row0 = blockIdx.x * 64;
    const int nr = min(64, nrows - row0);

    for (int i = tid; i < 64 * DIM / 4; i += 256) {
        int r = i >> 5;
        float4 v = make_float4(0.f, 0.f, 0.f, 0.f);
        if (r < nr) v = ((const float4*)(X + (size_t)row0 * DIM))[i];
        ((float4*)xs)[i] = v;
    }
    {
        const float4* wg = (const float4*)Wl;
        ((float4*)wsl[0])[tid] = wg[tid];
        ((float4*)wsl[0])[tid + 256] = wg[tid + 256];
    }
    __syncthreads();

    const int rg = tid >> 5;
    const int cg = tid & 31;
    const int rbase = rg * 8;
    const int c = cg * 4;

    float acc[8][4];
    #pragma unroll
    for (int i = 0; i < 8; ++i)
        #pragma unroll
        for (int j = 0; j < 4; ++j) acc[i][j] = 0.f;

    #pragma unroll 1
    for (int s = 0; s < 8; ++s) {
        const int cur = s & 1;
        float4 p0, p1;
        if (s < 7) {
            const float4* wg = (const float4*)(Wl + (size_t)(s + 1) * 16 * DIM);
            p0 = wg[tid];
            p1 = wg[tid + 256];
        }
        const float* wb = wsl[cur];
        #pragma unroll
        for (int kk = 0; kk < 16; kk += 4) {
            float4 w0 = *(const float4*)&wb[(kk + 0) * DIM + c];
            float4 w1 = *(const float4*)&wb[(kk + 1) * DIM + c];
            float4 w2 = *(const float4*)&wb[(kk + 2) * DIM + c];
            float4 w3 = *(const float4*)&wb[(kk + 3) * DIM + c];
            #pragma unroll
            for (int rr = 0; rr < 8; ++rr) {
                float4 xv = *(const float4*)&xs[(rbase + rr) * DIM + s * 16 + kk];
                acc[rr][0] += xv.x * w0.x + xv.y * w1.x + xv.z * w2.x + xv.w * w3.x;
                acc[rr][1] += xv.x * w0.y + xv.y * w1.y + xv.z * w2.y + xv.w * w3.y;
                acc[rr][2] += xv.x * w0.z + xv.y * w1.z + xv.z * w2.z + xv.w * w3.z;
                acc[rr][3] += xv.x * w0.w + xv.y * w1.w + xv.z * w2.w + xv.w * w3.w;
            }
        }
        if (s < 7) {
            ((float4*)wsl[cur ^ 1])[tid] = p0;
            ((float4*)wsl[cur ^ 1])[tid + 256] = p1;
        }
        __syncthreads();
    }

    #pragma unroll
    for (int rr = 0; rr < 8; ++rr) {
        int r = row0 + rbase + rr;
        if (r < nrows) {
            float dv = dinv[r];
            uint2 o;
            o.x = bf2(acc[rr][0] * dv, acc[rr][1] * dv);
            o.y = bf2(acc[rr][2] * dv, acc[rr][3] * dv);
            *(uint2*)&H2b[((size_t)r * DIM + c) >> 1] = o;
        }
    }
}

// ---------------- fused gather + residual + bias + LayerNorm + ReLU ---------
// One wave per node; lane owns dims [2*lane, 2*lane+1]. h2 is bf16-packed.
// Adjacency indices preloaded one-per-lane, broadcast via shuffle.

__launch_bounds__(256)
__global__ void gather_ln_kernel(const float* __restrict__ xcur, const u32* __restrict__ h2u,
                                 const float* __restrict__ dinv,
                                 const int* __restrict__ row_ptr, const int* __restrict__ csr_src,
                                 const float* __restrict__ bl, const float* __restrict__ gamma,
                                 const float* __restrict__ beta, float* __restrict__ xout) {
    int node = blockIdx.x * 4 + (threadIdx.x >> 6);
    if (node >= NN) return;
    int lane = threadIdx.x & 63;
    int beg = row_ptr[node];
    int end = row_ptr[node + 1];
    int deg = end - beg;

    // preload up to 64 neighbor indices, one per lane
    int myidx = (lane < deg) ? csr_src[beg + lane] : 0;

    u32 sv = h2u[(size_t)node * 64 + lane];  // self-loop term
    float sx = bflo(sv), sy = bfhi(sv);
    for (int e = 0; e < deg; ++e) {
        int sn = (e < 64) ? __shfl(myidx, e) : csr_src[beg + e];
        u32 v = h2u[(size_t)sn * 64 + lane];
        sx += bflo(v);
        sy += bfhi(v);
    }
    float dn = dinv[node];
    float2 xv = ((const float2*)(xcur + (size_t)node * DIM))[lane];
    float2 bv = ((const float2*)bl)[lane];
    float ax = xv.x + sx * dn + bv.x;
    float ay = xv.y + sy * dn + bv.y;

    float sum = ax + ay;
    float sq = ax * ax + ay * ay;
    #pragma unroll
    for (int o = 32; o > 0; o >>= 1) {
        sum += __shfl_xor(sum, o);
        sq += __shfl_xor(sq, o);
    }
    float mean = sum * (1.0f / DIM);
    float var = sq * (1.0f / DIM) - mean * mean;
    float rstd = rsqrtf(var + 1e-5f);
    float2 g = ((const float2*)gamma)[lane];
    float2 bt = ((const float2*)beta)[lane];
    float2 o;
    o.x = fmaxf((ax - mean) * rstd * g.x + bt.x, 0.f);
    o.y = fmaxf((ay - mean) * rstd * g.y + bt.y, 0.f);
    ((float2*)(xout + (size_t)node * DIM))[lane] = o;
}

// ---------------- global mean pool (batch is SORTED -> segments) ------------

__global__ void bounds_kernel(const int* __restrict__ batch, int* __restrict__ bounds) {
    int g = threadIdx.x;
    if (g > NGRAPH) return;
    int lo = 0, hi = NN;
    while (lo < hi) {
        int mid = (lo + hi) >> 1;
        if (batch[mid] < g) lo = mid + 1; else hi = mid;
    }
    bounds[g] = lo;
}

__launch_bounds__(256)
__global__ void pool_kernel(const float* __restrict__ x, const int* __restrict__ bounds,
                            float* __restrict__ out) {
    __shared__ float part[DIM];
    int g = blockIdx.x;
    int beg = bounds[g], end = bounds[g + 1];
    int half = threadIdx.x >> 7;
    int d = threadIdx.x & 127;
    float s = 0.f;
    for (int r = beg + half; r < end; r += 2)
        s += x[(size_t)r * DIM + d];
    if (half == 1) part[d] = s;
    __syncthreads();
    if (half == 0) {
        float tot = s + part[d];
        float cntf = (float)(end - beg);
        out[g * DIM + d] = tot / fmaxf(cntf, 1.0f);
    }
}

// ---------------- launch ----------------------------------------------------

extern "C" void kernel_launch(void* const* d_in, const int* in_sizes, int n_in,
                              void* d_out, int out_size, void* d_ws, size_t ws_size,
                              hipStream_t stream) {
    const float* x     = (const float*)d_in[0];
    const int*   ei    = (const int*)d_in[1];
    const int*   batch = (const int*)d_in[2];
    const float* W     = (const float*)d_in[3];
    const float* b     = (const float*)d_in[4];
    const float* gamma = (const float*)d_in[5];
    const float* beta  = (const float*)d_in[6];
    float* out = (float*)d_out;

    const int* srcE = ei;        // edge_index[0]
    const int* dstE = ei + NE;   // edge_index[1]

    // workspace layout
    char* p = (char*)d_ws;
    float* xA      = (float*)p;  p += (size_t)NN * DIM * sizeof(float);   // 25.6 MB
    u32*   h2b     = (u32*)p;    p += (size_t)NN * (DIM / 2) * sizeof(u32); // 12.8 MB (bf16)
    float* dinv    = (float*)p;  p += (size_t)NN * sizeof(float);
    int*   deg     = (int*)p;    p += (size_t)NN * sizeof(int);
    int*   ccnt    = (int*)p;    p += (size_t)NN * sizeof(int);
    int*   row_ptr = (int*)p;    p += (size_t)(NN + 1) * sizeof(int);
    int*   csr_src = (int*)p;    p += (size_t)NE * sizeof(int);
    int*   bounds  = (int*)p;    p += (size_t)(NGRAPH + 1) * sizeof(int);
    int*   bsum    = (int*)p;    p += (size_t)SCAN_BLOCKS * sizeof(int);

    // CSR build
    hipMemsetAsync(deg, 0, NN * sizeof(int), stream);
    hipMemsetAsync(ccnt, 0, NN * sizeof(int), stream);
    deg_kernel<<<(NE + 255) / 256, 256, 0, stream>>>(dstE, deg);
    blocksum_kernel<<<SCAN_BLOCKS, 256, 0, stream>>>(deg, bsum);
    scanb_kernel<<<1, 256, 0, stream>>>(bsum);
    rowptr_kernel<<<SCAN_BLOCKS, 256, 0, stream>>>(deg, bsum, row_ptr, dinv);
    fill_kernel<<<(NE + 255) / 256, 256, 0, stream>>>(srcE, dstE, row_ptr, ccnt, csr_src);
    bounds_kernel<<<1, 256, 0, stream>>>(batch, bounds);

    const float* xin = x;
    for (int l = 0; l < NLAYER; ++l) {
        gemm_kernel<<<(NN + 63) / 64, 256, 0, stream>>>(xin, W + (size_t)l * DIM * DIM, dinv, h2b, NN);
        gather_ln_kernel<<<(NN + 3) / 4, 256, 0, stream>>>(
            xin, h2b, dinv, row_ptr, csr_src, b + l * DIM, gamma + l * DIM, beta + l * DIM, xA);
        xin = xA;  // in-place safe: cross-row reads go through h2b only
    }

    pool_kernel<<<NGRAPH, 256, 0, stream>>>(xA, bounds, out);
}

// Round 7
// 403.635 us; speedup vs baseline: 11.4975x; 1.4062x over previous
//
#include <hip/hip_runtime.h>

// N=50000 nodes, E=600000 edges, D=128, L=4 layers, G=128 graphs.
#define NN 50000
#define NE 600000
#define DIM 128
#define NLAYER 4
#define NGRAPH 128
#define SCAN_BLOCKS ((NN + 255) / 256)   // 196
#define XS_STRIDE 136                    // bf16 elems per LDS row (128 + 8 pad)

typedef unsigned int u32;
typedef __attribute__((ext_vector_type(8))) short short8v;  // 8 x bf16 (4 VGPR)
typedef __attribute__((ext_vector_type(4))) float f32x4;

// pack two fp32 -> 2x bf16 (round-to-nearest-even)
__device__ __forceinline__ u32 bf2(float a, float b) {
    u32 ua = __float_as_uint(a);
    ua = (ua + 0x7fffu + ((ua >> 16) & 1u)) >> 16;
    u32 ub = __float_as_uint(b);
    ub = (ub + 0x7fffu + ((ub >> 16) & 1u)) >> 16;
    return ua | (ub << 16);
}
__device__ __forceinline__ unsigned short bf16r(float a) {
    u32 u = __float_as_uint(a);
    u = (u + 0x7fffu + ((u >> 16) & 1u)) >> 16;
    return (unsigned short)u;
}
__device__ __forceinline__ float bflo(u32 v) { return __uint_as_float(v << 16); }
__device__ __forceinline__ float bfhi(u32 v) { return __uint_as_float(v & 0xffff0000u); }

// ---------------- CSR build (edge structure only, once per launch) ----------

__global__ void deg_kernel(const int* __restrict__ dst, int* __restrict__ deg) {
    int e = blockIdx.x * blockDim.x + threadIdx.x;
    if (e < NE) atomicAdd(&deg[dst[e]], 1);
}

__launch_bounds__(256)
__global__ void blocksum_kernel(const int* __restrict__ deg, int* __restrict__ bsum) {
    int i = blockIdx.x * 256 + threadIdx.x;
    int v = (i < NN) ? deg[i] : 0;
    #pragma unroll
    for (int o = 32; o > 0; o >>= 1) v += __shfl_xor(v, o);
    __shared__ int ws[4];
    int wid = threadIdx.x >> 6;
    if ((threadIdx.x & 63) == 0) ws[wid] = v;
    __syncthreads();
    if (threadIdx.x == 0) bsum[blockIdx.x] = ws[0] + ws[1] + ws[2] + ws[3];
}

__launch_bounds__(256)
__global__ void scanb_kernel(int* __restrict__ bsum) {
    __shared__ int s[256];
    int tid = threadIdx.x;
    int v = (tid < SCAN_BLOCKS) ? bsum[tid] : 0;
    s[tid] = v;
    __syncthreads();
    for (int o = 1; o < 256; o <<= 1) {
        int t = (tid >= o) ? s[tid - o] : 0;
        __syncthreads();
        s[tid] += t;
        __syncthreads();
    }
    if (tid < SCAN_BLOCKS) bsum[tid] = s[tid] - v;  // exclusive
}

__launch_bounds__(256)
__global__ void rowptr_kernel(const int* __restrict__ deg, const int* __restrict__ bsum,
                              int* __restrict__ row_ptr, float* __restrict__ dinv) {
    __shared__ int s[256];
    int tid = threadIdx.x;
    int i = blockIdx.x * 256 + tid;
    int d = (i < NN) ? deg[i] : 0;
    s[tid] = d;
    __syncthreads();
    for (int o = 1; o < 256; o <<= 1) {
        int t = (tid >= o) ? s[tid - o] : 0;
        __syncthreads();
        s[tid] += t;
        __syncthreads();
    }
    if (i < NN) {
        row_ptr[i] = bsum[blockIdx.x] + s[tid] - d;  // exclusive prefix
        dinv[i] = rsqrtf((float)d + 1.0f);           // +1 self-loop
    }
    if (i == 0) row_ptr[NN] = NE;
}

__global__ void fill_kernel(const int* __restrict__ src, const int* __restrict__ dst,
                            const int* __restrict__ row_ptr, int* __restrict__ cnt,
                            int* __restrict__ csr_src) {
    int e = blockIdx.x * blockDim.x + threadIdx.x;
    if (e >= NE) return;
    int d = dst[e];
    int pos = row_ptr[d] + atomicAdd(&cnt[d], 1);
    csr_src[pos] = src[e];
}

// ---------------- one-time conversions --------------------------------------

// WT[l][n][k] = bf16(W[l][k][n])  (transposed so B-fragments are contiguous)
__global__ void wprep_kernel(const float* __restrict__ W, unsigned short* __restrict__ WT) {
    int t = blockIdx.x * 256 + threadIdx.x;
    if (t >= NLAYER * DIM * DIM) return;
    int l = t >> 14;
    int rem = t & 16383;
    int k = rem >> 7, n = rem & 127;
    WT[(size_t)l * 16384 + n * 128 + k] = bf16r(W[(size_t)l * 16384 + k * 128 + n]);
}

// xb = bf16 packed copy of x
__global__ void xconv_kernel(const float* __restrict__ x, u32* __restrict__ xb) {
    int t = blockIdx.x * 256 + threadIdx.x;
    if (t >= NN * 64) return;
    float2 v = ((const float2*)x)[t];
    xb[t] = bf2(v.x, v.y);
}

// ---------------- GEMM via MFMA: H2[N,128](bf16) = (Xb @ W) * dinv[row] -----
// 256 threads = 4 waves, 64-row tile. X tile + full WT staged in LDS with
// +8 bf16 row padding (row stride 272 B). Rows are 16 uint4 each; LDS row
// stride is 17 uint4. Per wave: 16 rows x 128 cols = 8 (16x16) tiles x
// 4 K-steps of mfma_f32_16x16x32_bf16.
// Layouts (m89-verified): A row=lane&15, k=8*(lane>>4)+j; B col=lane&15,
// same k; D col=lane&15, row=4*(lane>>4)+reg.

__launch_bounds__(256)
__global__ void gemm_mfma_kernel(const u32* __restrict__ Xb, const unsigned short* __restrict__ WTl,
                                 const float* __restrict__ dinv,
                                 unsigned short* __restrict__ H2s, int nrows) {
    __shared__ __align__(16) unsigned short xs[64 * XS_STRIDE];    // 17408 B
    __shared__ __align__(16) unsigned short wt[128 * XS_STRIDE];   // 34816 B
    const int tid = threadIdx.x;
    const int row0 = blockIdx.x * 64;
    const int nr = min(64, nrows - row0);

    // stage X tile: 64 rows x 16 uint4 (zero-fill past nr)
    {
        const uint4* xg = (const uint4*)(Xb + (size_t)row0 * 64);
        uint4* xs4 = (uint4*)xs;
        #pragma unroll
        for (int i = 0; i < 4; ++i) {
            int idx = i * 256 + tid;          // 0..1023
            int r = idx >> 4, c = idx & 15;   // 16 uint4 per row
            uint4 v = make_uint4(0u, 0u, 0u, 0u);
            if (r < nr) v = xg[idx];
            xs4[r * 17 + c] = v;
        }
    }
    // stage WT: 128 rows x 16 uint4
    {
        const uint4* wg = (const uint4*)WTl;
        uint4* wt4 = (uint4*)wt;
        #pragma unroll
        for (int i = 0; i < 8; ++i) {
            int idx = i * 256 + tid;          // 0..2047
            int r = idx >> 4, c = idx & 15;
            wt4[r * 17 + c] = wg[idx];
        }
    }
    __syncthreads();

    const int wave = tid >> 6;
    const int lane = tid & 63;
    const int lrow = lane & 15;   // A row / B col within tile
    const int kg = lane >> 4;     // k-group: k = 32*kc + 8*kg + j

    // A fragments: 4 k-chunks for this wave's 16 rows
    short8v a[4];
    #pragma unroll
    for (int kc = 0; kc < 4; ++kc)
        a[kc] = *(const short8v*)&xs[(wave * 16 + lrow) * XS_STRIDE + kc * 32 + kg * 8];

    f32x4 acc[8];
    #pragma unroll
    for (int t = 0; t < 8; ++t) acc[t] = (f32x4){0.f, 0.f, 0.f, 0.f};

    #pragma unroll
    for (int t = 0; t < 8; ++t) {
        #pragma unroll
        for (int kc = 0; kc < 4; ++kc) {
            short8v bfrag = *(const short8v*)&wt[(t * 16 + lrow) * XS_STRIDE + kc * 32 + kg * 8];
            acc[t] = __builtin_amdgcn_mfma_f32_16x16x32_bf16(a[kc], bfrag, acc[t], 0, 0, 0);
        }
    }

    // epilogue: scale by dinv, store bf16
    #pragma unroll
    for (int r = 0; r < 4; ++r) {
        int row = row0 + wave * 16 + 4 * kg + r;
        if (row < nrows) {
            float dv = dinv[row];
            #pragma unroll
            for (int t = 0; t < 8; ++t)
                H2s[(size_t)row * DIM + t * 16 + lrow] = bf16r(acc[t][r] * dv);
        }
    }
}

// ---------------- fused gather + residual + bias + LayerNorm + ReLU ---------
// One wave per node; lane owns dims [2*lane, 2*lane+1]. h2 is bf16-packed.
// Writes fp32 x (residual/pool) AND bf16 x (next layer's GEMM input).

__launch_bounds__(256)
__global__ void gather_ln_kernel(const float* __restrict__ xcur, const u32* __restrict__ h2u,
                                 const float* __restrict__ dinv,
                                 const int* __restrict__ row_ptr, const int* __restrict__ csr_src,
                                 const float* __restrict__ bl, const float* __restrict__ gamma,
                                 const float* __restrict__ beta, float* __restrict__ xout,
                                 u32* __restrict__ xbout) {
    int node = blockIdx.x * 4 + (threadIdx.x >> 6);
    if (node >= NN) return;
    int lane = threadIdx.x & 63;
    int beg = row_ptr[node];
    int end = row_ptr[node + 1];
    int deg = end - beg;

    int myidx = (lane < deg) ? csr_src[beg + lane] : 0;

    u32 sv = h2u[(size_t)node * 64 + lane];  // self-loop term
    float sx = bflo(sv), sy = bfhi(sv);
    for (int e = 0; e < deg; ++e) {
        int sn = (e < 64) ? __shfl(myidx, e) : csr_src[beg + e];
        u32 v = h2u[(size_t)sn * 64 + lane];
        sx += bflo(v);
        sy += bfhi(v);
    }
    float dn = dinv[node];
    float2 xv = ((const float2*)(xcur + (size_t)node * DIM))[lane];
    float2 bv = ((const float2*)bl)[lane];
    float ax = xv.x + sx * dn + bv.x;
    float ay = xv.y + sy * dn + bv.y;

    float sum = ax + ay;
    float sq = ax * ax + ay * ay;
    #pragma unroll
    for (int o = 32; o > 0; o >>= 1) {
        sum += __shfl_xor(sum, o);
        sq += __shfl_xor(sq, o);
    }
    float mean = sum * (1.0f / DIM);
    float var = sq * (1.0f / DIM) - mean * mean;
    float rstd = rsqrtf(var + 1e-5f);
    float2 g = ((const float2*)gamma)[lane];
    float2 bt = ((const float2*)beta)[lane];
    float2 o;
    o.x = fmaxf((ax - mean) * rstd * g.x + bt.x, 0.f);
    o.y = fmaxf((ay - mean) * rstd * g.y + bt.y, 0.f);
    ((float2*)(xout + (size_t)node * DIM))[lane] = o;
    xbout[(size_t)node * 64 + lane] = bf2(o.x, o.y);
}

// ---------------- global mean pool (batch is SORTED -> segments) ------------

__global__ void bounds_kernel(const int* __restrict__ batch, int* __restrict__ bounds) {
    int g = threadIdx.x;
    if (g > NGRAPH) return;
    int lo = 0, hi = NN;
    while (lo < hi) {
        int mid = (lo + hi) >> 1;
        if (batch[mid] < g) lo = mid + 1; else hi = mid;
    }
    bounds[g] = lo;
}

__launch_bounds__(256)
__global__ void pool_kernel(const float* __restrict__ x, const int* __restrict__ bounds,
                            float* __restrict__ out) {
    __shared__ float part[DIM];
    int g = blockIdx.x;
    int beg = bounds[g], end = bounds[g + 1];
    int half = threadIdx.x >> 7;
    int d = threadIdx.x & 127;
    float s = 0.f;
    for (int r = beg + half; r < end; r += 2)
        s += x[(size_t)r * DIM + d];
    if (half == 1) part[d] = s;
    __syncthreads();
    if (half == 0) {
        float tot = s + part[d];
        float cntf = (float)(end - beg);
        out[g * DIM + d] = tot / fmaxf(cntf, 1.0f);
    }
}

// ---------------- launch ----------------------------------------------------

extern "C" void kernel_launch(void* const* d_in, const int* in_sizes, int n_in,
                              void* d_out, int out_size, void* d_ws, size_t ws_size,
                              hipStream_t stream) {
    const float* x     = (const float*)d_in[0];
    const int*   ei    = (const int*)d_in[1];
    const int*   batch = (const int*)d_in[2];
    const float* W     = (const float*)d_in[3];
    const float* b     = (const float*)d_in[4];
    const float* gamma = (const float*)d_in[5];
    const float* beta  = (const float*)d_in[6];
    float* out = (float*)d_out;

    const int* srcE = ei;        // edge_index[0]
    const int* dstE = ei + NE;   // edge_index[1]

    // workspace layout
    char* p = (char*)d_ws;
    float* xA      = (float*)p;  p += (size_t)NN * DIM * sizeof(float);        // 25.6 MB
    u32*   xb      = (u32*)p;    p += (size_t)NN * (DIM / 2) * sizeof(u32);    // 12.8 MB
    unsigned short* h2s = (unsigned short*)p; p += (size_t)NN * DIM * sizeof(unsigned short); // 12.8 MB
    unsigned short* WT  = (unsigned short*)p; p += (size_t)NLAYER * DIM * DIM * sizeof(unsigned short);
    float* dinv    = (float*)p;  p += (size_t)NN * sizeof(float);
    int*   deg     = (int*)p;    p += (size_t)NN * sizeof(int);
    int*   ccnt    = (int*)p;    p += (size_t)NN * sizeof(int);
    int*   row_ptr = (int*)p;    p += (size_t)(NN + 1) * sizeof(int);
    int*   csr_src = (int*)p;    p += (size_t)NE * sizeof(int);
    int*   bounds  = (int*)p;    p += (size_t)(NGRAPH + 1) * sizeof(int);
    int*   bsum    = (int*)p;    p += (size_t)SCAN_BLOCKS * sizeof(int);

    // CSR build
    hipMemsetAsync(deg, 0, NN * sizeof(int), stream);
    hipMemsetAsync(ccnt, 0, NN * sizeof(int), stream);
    deg_kernel<<<(NE + 255) / 256, 256, 0, stream>>>(dstE, deg);
    blocksum_kernel<<<SCAN_BLOCKS, 256, 0, stream>>>(deg, bsum);
    scanb_kernel<<<1, 256, 0, stream>>>(bsum);
    rowptr_kernel<<<SCAN_BLOCKS, 256, 0, stream>>>(deg, bsum, row_ptr, dinv);
    fill_kernel<<<(NE + 255) / 256, 256, 0, stream>>>(srcE, dstE, row_ptr, ccnt, csr_src);
    bounds_kernel<<<1, 256, 0, stream>>>(batch, bounds);

    // one-time conversions
    wprep_kernel<<<(NLAYER * DIM * DIM + 255) / 256, 256, 0, stream>>>(W, WT);
    xconv_kernel<<<(NN * 64 + 255) / 256, 256, 0, stream>>>(x, xb);

    const float* xin = x;
    for (int l = 0; l < NLAYER; ++l) {
        gemm_mfma_kernel<<<(NN + 63) / 64, 256, 0, stream>>>(
            xb, WT + (size_t)l * DIM * DIM, dinv, h2s, NN);
        gather_ln_kernel<<<(NN + 3) / 4, 256, 0, stream>>>(
            xin, (const u32*)h2s, dinv, row_ptr, csr_src,
            b + l * DIM, gamma + l * DIM, beta + l * DIM, xA, xb);
        xin = xA;
    }

    pool_kernel<<<NGRAPH, 256, 0, stream>>>(xA, bounds, out);
}

// Round 8
// 367.765 us; speedup vs baseline: 12.6189x; 1.0975x over previous
//
#include <hip/hip_runtime.h>

// N=50000 nodes, E=600000 edges, D=128, L=4 layers, G=128 graphs.
#define NN 50000
#define NE 600000
#define DIM 128
#define NLAYER 4
#define NGRAPH 128
#define SCAN_BLOCKS ((NN + 255) / 256)   // 196
#define XS_STRIDE 136                    // bf16 elems per LDS row (128 + 8 pad)
#define POOL_SPLIT 4                     // blocks per graph in pool stage 1

typedef unsigned int u32;
typedef __attribute__((ext_vector_type(8))) short short8v;  // 8 x bf16 (4 VGPR)
typedef __attribute__((ext_vector_type(4))) float f32x4;

// pack two fp32 -> 2x bf16 (round-to-nearest-even)
__device__ __forceinline__ u32 bf2(float a, float b) {
    u32 ua = __float_as_uint(a);
    ua = (ua + 0x7fffu + ((ua >> 16) & 1u)) >> 16;
    u32 ub = __float_as_uint(b);
    ub = (ub + 0x7fffu + ((ub >> 16) & 1u)) >> 16;
    return ua | (ub << 16);
}
__device__ __forceinline__ unsigned short bf16r(float a) {
    u32 u = __float_as_uint(a);
    u = (u + 0x7fffu + ((u >> 16) & 1u)) >> 16;
    return (unsigned short)u;
}
__device__ __forceinline__ float bflo(u32 v) { return __uint_as_float(v << 16); }
__device__ __forceinline__ float bfhi(u32 v) { return __uint_as_float(v & 0xffff0000u); }

// ---------------- CSR build (edge structure only, once per launch) ----------

__global__ void deg_kernel(const int* __restrict__ dst, int* __restrict__ deg) {
    int e = blockIdx.x * blockDim.x + threadIdx.x;
    if (e < NE) atomicAdd(&deg[dst[e]], 1);
}

__launch_bounds__(256)
__global__ void blocksum_kernel(const int* __restrict__ deg, int* __restrict__ bsum) {
    int i = blockIdx.x * 256 + threadIdx.x;
    int v = (i < NN) ? deg[i] : 0;
    #pragma unroll
    for (int o = 32; o > 0; o >>= 1) v += __shfl_xor(v, o);
    __shared__ int ws[4];
    int wid = threadIdx.x >> 6;
    if ((threadIdx.x & 63) == 0) ws[wid] = v;
    __syncthreads();
    if (threadIdx.x == 0) bsum[blockIdx.x] = ws[0] + ws[1] + ws[2] + ws[3];
}

__launch_bounds__(256)
__global__ void scanb_kernel(int* __restrict__ bsum) {
    __shared__ int s[256];
    int tid = threadIdx.x;
    int v = (tid < SCAN_BLOCKS) ? bsum[tid] : 0;
    s[tid] = v;
    __syncthreads();
    for (int o = 1; o < 256; o <<= 1) {
        int t = (tid >= o) ? s[tid - o] : 0;
        __syncthreads();
        s[tid] += t;
        __syncthreads();
    }
    if (tid < SCAN_BLOCKS) bsum[tid] = s[tid] - v;  // exclusive
}

__launch_bounds__(256)
__global__ void rowptr_kernel(const int* __restrict__ deg, const int* __restrict__ bsum,
                              int* __restrict__ row_ptr, float* __restrict__ dinv) {
    __shared__ int s[256];
    int tid = threadIdx.x;
    int i = blockIdx.x * 256 + tid;
    int d = (i < NN) ? deg[i] : 0;
    s[tid] = d;
    __syncthreads();
    for (int o = 1; o < 256; o <<= 1) {
        int t = (tid >= o) ? s[tid - o] : 0;
        __syncthreads();
        s[tid] += t;
        __syncthreads();
    }
    if (i < NN) {
        row_ptr[i] = bsum[blockIdx.x] + s[tid] - d;  // exclusive prefix
        dinv[i] = rsqrtf((float)d + 1.0f);           // +1 self-loop
    }
    if (i == 0) row_ptr[NN] = NE;
}

__global__ void fill_kernel(const int* __restrict__ src, const int* __restrict__ dst,
                            const int* __restrict__ row_ptr, int* __restrict__ cnt,
                            int* __restrict__ csr_src) {
    int e = blockIdx.x * blockDim.x + threadIdx.x;
    if (e >= NE) return;
    int d = dst[e];
    int pos = row_ptr[d] + atomicAdd(&cnt[d], 1);
    csr_src[pos] = src[e];
}

// ---------------- one-time conversions --------------------------------------

// WT[l][n][k] = bf16(W[l][k][n])  (transposed so B-fragments are contiguous)
__global__ void wprep_kernel(const float* __restrict__ W, unsigned short* __restrict__ WT) {
    int t = blockIdx.x * 256 + threadIdx.x;
    if (t >= NLAYER * DIM * DIM) return;
    int l = t >> 14;
    int rem = t & 16383;
    int k = rem >> 7, n = rem & 127;
    WT[(size_t)l * 16384 + n * 128 + k] = bf16r(W[(size_t)l * 16384 + k * 128 + n]);
}

// xb = bf16 packed copy of x
__global__ void xconv_kernel(const float* __restrict__ x, u32* __restrict__ xb) {
    int t = blockIdx.x * 256 + threadIdx.x;
    if (t >= NN * 64) return;
    float2 v = ((const float2*)x)[t];
    xb[t] = bf2(v.x, v.y);
}

// ---------------- GEMM via MFMA: H2[N,128](bf16) = (Xb @ W) * dinv[row] -----
// 256 threads = 4 waves, 64-row tile. X tile + full WT staged in LDS with
// +8 bf16 row padding (row stride 272 B). Rows are 16 uint4 each; LDS row
// stride is 17 uint4. Per wave: 16 rows x 128 cols = 8 (16x16) tiles x
// 4 K-steps of mfma_f32_16x16x32_bf16.
// Layouts (m89-verified): A row=lane&15, k=8*(lane>>4)+j; B col=lane&15,
// same k; D col=lane&15, row=4*(lane>>4)+reg.

__launch_bounds__(256)
__global__ void gemm_mfma_kernel(const u32* __restrict__ Xb, const unsigned short* __restrict__ WTl,
                                 const float* __restrict__ dinv,
                                 unsigned short* __restrict__ H2s, int nrows) {
    __shared__ __align__(16) unsigned short xs[64 * XS_STRIDE];    // 17408 B
    __shared__ __align__(16) unsigned short wt[128 * XS_STRIDE];   // 34816 B
    const int tid = threadIdx.x;
    const int row0 = blockIdx.x * 64;
    const int nr = min(64, nrows - row0);

    // stage X tile: 64 rows x 16 uint4 (zero-fill past nr)
    {
        const uint4* xg = (const uint4*)(Xb + (size_t)row0 * 64);
        uint4* xs4 = (uint4*)xs;
        #pragma unroll
        for (int i = 0; i < 4; ++i) {
            int idx = i * 256 + tid;          // 0..1023
            int r = idx >> 4, c = idx & 15;   // 16 uint4 per row
            uint4 v = make_uint4(0u, 0u, 0u, 0u);
            if (r < nr) v = xg[idx];
            xs4[r * 17 + c] = v;
        }
    }
    // stage WT: 128 rows x 16 uint4
    {
        const uint4* wg = (const uint4*)WTl;
        uint4* wt4 = (uint4*)wt;
        #pragma unroll
        for (int i = 0; i < 8; ++i) {
            int idx = i * 256 + tid;          // 0..2047
            int r = idx >> 4, c = idx & 15;
            wt4[r * 17 + c] = wg[idx];
        }
    }
    __syncthreads();

    const int wave = tid >> 6;
    const int lane = tid & 63;
    const int lrow = lane & 15;   // A row / B col within tile
    const int kg = lane >> 4;     // k-group: k = 32*kc + 8*kg + j

    // A fragments: 4 k-chunks for this wave's 16 rows
    short8v a[4];
    #pragma unroll
    for (int kc = 0; kc < 4; ++kc)
        a[kc] = *(const short8v*)&xs[(wave * 16 + lrow) * XS_STRIDE + kc * 32 + kg * 8];

    f32x4 acc[8];
    #pragma unroll
    for (int t = 0; t < 8; ++t) acc[t] = (f32x4){0.f, 0.f, 0.f, 0.f};

    #pragma unroll
    for (int t = 0; t < 8; ++t) {
        #pragma unroll
        for (int kc = 0; kc < 4; ++kc) {
            short8v bfrag = *(const short8v*)&wt[(t * 16 + lrow) * XS_STRIDE + kc * 32 + kg * 8];
            acc[t] = __builtin_amdgcn_mfma_f32_16x16x32_bf16(a[kc], bfrag, acc[t], 0, 0, 0);
        }
    }

    // epilogue: scale by dinv, store bf16
    #pragma unroll
    for (int r = 0; r < 4; ++r) {
        int row = row0 + wave * 16 + 4 * kg + r;
        if (row < nrows) {
            float dv = dinv[row];
            #pragma unroll
            for (int t = 0; t < 8; ++t)
                H2s[(size_t)row * DIM + t * 16 + lrow] = bf16r(acc[t][r] * dv);
        }
    }
}

// ---------------- fused gather + residual + bias + LayerNorm + ReLU ---------
// One wave per node; lane owns dims [2*lane, 2*lane+1]. h2 is bf16-packed.
// Writes fp32 x (residual/pool) AND bf16 x (next layer's GEMM input).

__launch_bounds__(256)
__global__ void gather_ln_kernel(const float* __restrict__ xcur, const u32* __restrict__ h2u,
                                 const float* __restrict__ dinv,
                                 const int* __restrict__ row_ptr, const int* __restrict__ csr_src,
                                 const float* __restrict__ bl, const float* __restrict__ gamma,
                                 const float* __restrict__ beta, float* __restrict__ xout,
                                 u32* __restrict__ xbout) {
    int node = blockIdx.x * 4 + (threadIdx.x >> 6);
    if (node >= NN) return;
    int lane = threadIdx.x & 63;
    int beg = row_ptr[node];
    int end = row_ptr[node + 1];
    int deg = end - beg;

    int myidx = (lane < deg) ? csr_src[beg + lane] : 0;

    u32 sv = h2u[(size_t)node * 64 + lane];  // self-loop term
    float sx = bflo(sv), sy = bfhi(sv);
    for (int e = 0; e < deg; ++e) {
        int sn = (e < 64) ? __shfl(myidx, e) : csr_src[beg + e];
        u32 v = h2u[(size_t)sn * 64 + lane];
        sx += bflo(v);
        sy += bfhi(v);
    }
    float dn = dinv[node];
    float2 xv = ((const float2*)(xcur + (size_t)node * DIM))[lane];
    float2 bv = ((const float2*)bl)[lane];
    float ax = xv.x + sx * dn + bv.x;
    float ay = xv.y + sy * dn + bv.y;

    float sum = ax + ay;
    float sq = ax * ax + ay * ay;
    #pragma unroll
    for (int o = 32; o > 0; o >>= 1) {
        sum += __shfl_xor(sum, o);
        sq += __shfl_xor(sq, o);
    }
    float mean = sum * (1.0f / DIM);
    float var = sq * (1.0f / DIM) - mean * mean;
    float rstd = rsqrtf(var + 1e-5f);
    float2 g = ((const float2*)gamma)[lane];
    float2 bt = ((const float2*)beta)[lane];
    float2 o;
    o.x = fmaxf((ax - mean) * rstd * g.x + bt.x, 0.f);
    o.y = fmaxf((ay - mean) * rstd * g.y + bt.y, 0.f);
    ((float2*)(xout + (size_t)node * DIM))[lane] = o;
    xbout[(size_t)node * 64 + lane] = bf2(o.x, o.y);
}

// ---------------- global mean pool (batch is SORTED -> segments) ------------

__global__ void bounds_kernel(const int* __restrict__ batch, int* __restrict__ bounds) {
    int g = threadIdx.x;
    if (g > NGRAPH) return;
    int lo = 0, hi = NN;
    while (lo < hi) {
        int mid = (lo + hi) >> 1;
        if (batch[mid] < g) lo = mid + 1; else hi = mid;
    }
    bounds[g] = lo;
}

// stage 1: 4 blocks per graph, each sums a quarter of the segment -> partials
__launch_bounds__(256)
__global__ void pool1_kernel(const float* __restrict__ x, const int* __restrict__ bounds,
                             float* __restrict__ partials) {
    __shared__ float part[DIM];
    int g = blockIdx.x >> 2;
    int q = blockIdx.x & 3;
    int beg = bounds[g], end = bounds[g + 1];
    int len = end - beg;
    int qbeg = beg + (int)(((long long)len * q) >> 2);
    int qend = beg + (int)(((long long)len * (q + 1)) >> 2);
    int half = threadIdx.x >> 7;
    int d = threadIdx.x & 127;
    float s = 0.f;
    for (int r = qbeg + half; r < qend; r += 2)
        s += x[(size_t)r * DIM + d];
    if (half == 1) part[d] = s;
    __syncthreads();
    if (half == 0) partials[(size_t)blockIdx.x * DIM + d] = s + part[d];
}

// stage 2: combine 4 partials per graph, divide by count, write out
__launch_bounds__(256)
__global__ void pool2_kernel(const float* __restrict__ partials, const int* __restrict__ bounds,
                             float* __restrict__ out) {
    int t = blockIdx.x * 256 + threadIdx.x;
    if (t >= NGRAPH * DIM) return;
    int g = t >> 7;
    int d = t & 127;
    float s = partials[(size_t)(4 * g + 0) * DIM + d] + partials[(size_t)(4 * g + 1) * DIM + d] +
              partials[(size_t)(4 * g + 2) * DIM + d] + partials[(size_t)(4 * g + 3) * DIM + d];
    float cntf = (float)(bounds[g + 1] - bounds[g]);
    out[t] = s / fmaxf(cntf, 1.0f);
}

// ---------------- launch ----------------------------------------------------

extern "C" void kernel_launch(void* const* d_in, const int* in_sizes, int n_in,
                              void* d_out, int out_size, void* d_ws, size_t ws_size,
                              hipStream_t stream) {
    const float* x     = (const float*)d_in[0];
    const int*   ei    = (const int*)d_in[1];
    const int*   batch = (const int*)d_in[2];
    const float* W     = (const float*)d_in[3];
    const float* b     = (const float*)d_in[4];
    const float* gamma = (const float*)d_in[5];
    const float* beta  = (const float*)d_in[6];
    float* out = (float*)d_out;

    const int* srcE = ei;        // edge_index[0]
    const int* dstE = ei + NE;   // edge_index[1]

    // workspace layout
    char* p = (char*)d_ws;
    float* xA      = (float*)p;  p += (size_t)NN * DIM * sizeof(float);        // 25.6 MB
    u32*   xb      = (u32*)p;    p += (size_t)NN * (DIM / 2) * sizeof(u32);    // 12.8 MB
    unsigned short* h2s = (unsigned short*)p; p += (size_t)NN * DIM * sizeof(unsigned short); // 12.8 MB
    unsigned short* WT  = (unsigned short*)p; p += (size_t)NLAYER * DIM * DIM * sizeof(unsigned short);
    float* dinv    = (float*)p;  p += (size_t)NN * sizeof(float);
    int*   deg     = (int*)p;    p += (size_t)NN * sizeof(int);
    int*   ccnt    = (int*)p;    p += (size_t)NN * sizeof(int);
    int*   row_ptr = (int*)p;    p += (size_t)(NN + 1) * sizeof(int);
    int*   csr_src = (int*)p;    p += (size_t)NE * sizeof(int);
    int*   bounds  = (int*)p;    p += (size_t)(NGRAPH + 1) * sizeof(int);
    int*   bsum    = (int*)p;    p += (size_t)SCAN_BLOCKS * sizeof(int);
    float* partials = (float*)p; p += (size_t)NGRAPH * POOL_SPLIT * DIM * sizeof(float);

    // CSR build
    hipMemsetAsync(deg, 0, NN * sizeof(int), stream);
    hipMemsetAsync(ccnt, 0, NN * sizeof(int), stream);
    deg_kernel<<<(NE + 255) / 256, 256, 0, stream>>>(dstE, deg);
    blocksum_kernel<<<SCAN_BLOCKS, 256, 0, stream>>>(deg, bsum);
    scanb_kernel<<<1, 256, 0, stream>>>(bsum);
    rowptr_kernel<<<SCAN_BLOCKS, 256, 0, stream>>>(deg, bsum, row_ptr, dinv);
    fill_kernel<<<(NE + 255) / 256, 256, 0, stream>>>(srcE, dstE, row_ptr, ccnt, csr_src);
    bounds_kernel<<<1, 256, 0, stream>>>(batch, bounds);

    // one-time conversions
    wprep_kernel<<<(NLAYER * DIM * DIM + 255) / 256, 256, 0, stream>>>(W, WT);
    xconv_kernel<<<(NN * 64 + 255) / 256, 256, 0, stream>>>(x, xb);

    const float* xin = x;
    for (int l = 0; l < NLAYER; ++l) {
        gemm_mfma_kernel<<<(NN + 63) / 64, 256, 0, stream>>>(
            xb, WT + (size_t)l * DIM * DIM, dinv, h2s, NN);
        gather_ln_kernel<<<(NN + 3) / 4, 256, 0, stream>>>(
            xin, (const u32*)h2s, dinv, row_ptr, csr_src,
            b + l * DIM, gamma + l * DIM, beta + l * DIM, xA, xb);
        xin = xA;
    }

    pool1_kernel<<<NGRAPH * POOL_SPLIT, 256, 0, stream>>>(xA, bounds, partials);
    pool2_kernel<<<(NGRAPH * DIM + 255) / 256, 256, 0, stream>>>(partials, bounds, out);
}

// Round 9
// 304.309 us; speedup vs baseline: 15.2502x; 1.2085x over previous
//
#include <hip/hip_runtime.h>

// N=50000 nodes, E=600000 edges, D=128, L=4 layers, G=128 graphs.
#define NN 50000
#define NE 600000
#define DIM 128
#define NLAYER 4
#define NGRAPH 128
#define SCAN_BLOCKS ((NN + 255) / 256)   // 196
#define XS_STRIDE 136                    // bf16 elems per LDS row (128 + 8 pad)
#define POOL_SPLIT 4                     // blocks per graph in pool stage 1

typedef unsigned int u32;
typedef __attribute__((ext_vector_type(8))) short short8v;  // 8 x bf16 (4 VGPR)
typedef __attribute__((ext_vector_type(4))) float f32x4;

// pack two fp32 -> 2x bf16 (round-to-nearest-even)
__device__ __forceinline__ u32 bf2(float a, float b) {
    u32 ua = __float_as_uint(a);
    ua = (ua + 0x7fffu + ((ua >> 16) & 1u)) >> 16;
    u32 ub = __float_as_uint(b);
    ub = (ub + 0x7fffu + ((ub >> 16) & 1u)) >> 16;
    return ua | (ub << 16);
}
__device__ __forceinline__ unsigned short bf16r(float a) {
    u32 u = __float_as_uint(a);
    u = (u + 0x7fffu + ((u >> 16) & 1u)) >> 16;
    return (unsigned short)u;
}
__device__ __forceinline__ float bflo(u32 v) { return __uint_as_float(v << 16); }
__device__ __forceinline__ float bfhi(u32 v) { return __uint_as_float(v & 0xffff0000u); }

// ---------------- CSR build (edge structure only, once per launch) ----------

__global__ void deg_kernel(const int* __restrict__ dst, int* __restrict__ deg) {
    int e = blockIdx.x * blockDim.x + threadIdx.x;
    if (e < NE) atomicAdd(&deg[dst[e]], 1);
}

__launch_bounds__(256)
__global__ void blocksum_kernel(const int* __restrict__ deg, int* __restrict__ bsum) {
    int i = blockIdx.x * 256 + threadIdx.x;
    int v = (i < NN) ? deg[i] : 0;
    #pragma unroll
    for (int o = 32; o > 0; o >>= 1) v += __shfl_xor(v, o);
    __shared__ int ws[4];
    int wid = threadIdx.x >> 6;
    if ((threadIdx.x & 63) == 0) ws[wid] = v;
    __syncthreads();
    if (threadIdx.x == 0) bsum[blockIdx.x] = ws[0] + ws[1] + ws[2] + ws[3];
}

__launch_bounds__(256)
__global__ void scanb_kernel(int* __restrict__ bsum) {
    __shared__ int s[256];
    int tid = threadIdx.x;
    int v = (tid < SCAN_BLOCKS) ? bsum[tid] : 0;
    s[tid] = v;
    __syncthreads();
    for (int o = 1; o < 256; o <<= 1) {
        int t = (tid >= o) ? s[tid - o] : 0;
        __syncthreads();
        s[tid] += t;
        __syncthreads();
    }
    if (tid < SCAN_BLOCKS) bsum[tid] = s[tid] - v;  // exclusive
}

__launch_bounds__(256)
__global__ void rowptr_kernel(const int* __restrict__ deg, const int* __restrict__ bsum,
                              int* __restrict__ row_ptr, float* __restrict__ dinv) {
    __shared__ int s[256];
    int tid = threadIdx.x;
    int i = blockIdx.x * 256 + tid;
    int d = (i < NN) ? deg[i] : 0;
    s[tid] = d;
    __syncthreads();
    for (int o = 1; o < 256; o <<= 1) {
        int t = (tid >= o) ? s[tid - o] : 0;
        __syncthreads();
        s[tid] += t;
        __syncthreads();
    }
    if (i < NN) {
        row_ptr[i] = bsum[blockIdx.x] + s[tid] - d;  // exclusive prefix
        dinv[i] = rsqrtf((float)d + 1.0f);           // +1 self-loop
    }
    if (i == 0) row_ptr[NN] = NE;
}

__global__ void fill_kernel(const int* __restrict__ src, const int* __restrict__ dst,
                            const int* __restrict__ row_ptr, int* __restrict__ cnt,
                            int* __restrict__ csr_src) {
    int e = blockIdx.x * blockDim.x + threadIdx.x;
    if (e >= NE) return;
    int d = dst[e];
    int pos = row_ptr[d] + atomicAdd(&cnt[d], 1);
    csr_src[pos] = src[e];
}

// ---------------- one-time conversions --------------------------------------

// WT[l][n][k] = bf16(W[l][k][n])  (transposed so B-fragments are contiguous)
__global__ void wprep_kernel(const float* __restrict__ W, unsigned short* __restrict__ WT) {
    int t = blockIdx.x * 256 + threadIdx.x;
    if (t >= NLAYER * DIM * DIM) return;
    int l = t >> 14;
    int rem = t & 16383;
    int k = rem >> 7, n = rem & 127;
    WT[(size_t)l * 16384 + n * 128 + k] = bf16r(W[(size_t)l * 16384 + k * 128 + n]);
}

// xb = bf16 packed copy of x
__global__ void xconv_kernel(const float* __restrict__ x, u32* __restrict__ xb) {
    int t = blockIdx.x * 256 + threadIdx.x;
    if (t >= NN * 64) return;
    float2 v = ((const float2*)x)[t];
    xb[t] = bf2(v.x, v.y);
}

// ---------------- GEMM via MFMA: H2[N,128](bf16) = (Xb @ W) * dinv[row] -----
// 256 threads = 4 waves, 64-row tile. X tile + full WT staged in LDS with
// +8 bf16 row padding (row stride 272 B). Rows are 16 uint4 each; LDS row
// stride is 17 uint4. Per wave: 16 rows x 128 cols = 8 (16x16) tiles x
// 4 K-steps of mfma_f32_16x16x32_bf16.
// Layouts (m89-verified): A row=lane&15, k=8*(lane>>4)+j; B col=lane&15,
// same k; D col=lane&15, row=4*(lane>>4)+reg.

__launch_bounds__(256)
__global__ void gemm_mfma_kernel(const u32* __restrict__ Xb, const unsigned short* __restrict__ WTl,
                                 const float* __restrict__ dinv,
                                 unsigned short* __restrict__ H2s, int nrows) {
    __shared__ __align__(16) unsigned short xs[64 * XS_STRIDE];    // 17408 B
    __shared__ __align__(16) unsigned short wt[128 * XS_STRIDE];   // 34816 B
    const int tid = threadIdx.x;
    const int row0 = blockIdx.x * 64;
    const int nr = min(64, nrows - row0);

    // stage X tile: 64 rows x 16 uint4 (zero-fill past nr)
    {
        const uint4* xg = (const uint4*)(Xb + (size_t)row0 * 64);
        uint4* xs4 = (uint4*)xs;
        #pragma unroll
        for (int i = 0; i < 4; ++i) {
            int idx = i * 256 + tid;          // 0..1023
            int r = idx >> 4, c = idx & 15;   // 16 uint4 per row
            uint4 v = make_uint4(0u, 0u, 0u, 0u);
            if (r < nr) v = xg[idx];
            xs4[r * 17 + c] = v;
        }
    }
    // stage WT: 128 rows x 16 uint4
    {
        const uint4* wg = (const uint4*)WTl;
        uint4* wt4 = (uint4*)wt;
        #pragma unroll
        for (int i = 0; i < 8; ++i) {
            int idx = i * 256 + tid;          // 0..2047
            int r = idx >> 4, c = idx & 15;
            wt4[r * 17 + c] = wg[idx];
        }
    }
    __syncthreads();

    const int wave = tid >> 6;
    const int lane = tid & 63;
    const int lrow = lane & 15;   // A row / B col within tile
    const int kg = lane >> 4;     // k-group: k = 32*kc + 8*kg + j

    // A fragments: 4 k-chunks for this wave's 16 rows
    short8v a[4];
    #pragma unroll
    for (int kc = 0; kc < 4; ++kc)
        a[kc] = *(const short8v*)&xs[(wave * 16 + lrow) * XS_STRIDE + kc * 32 + kg * 8];

    f32x4 acc[8];
    #pragma unroll
    for (int t = 0; t < 8; ++t) acc[t] = (f32x4){0.f, 0.f, 0.f, 0.f};

    #pragma unroll
    for (int t = 0; t < 8; ++t) {
        #pragma unroll
        for (int kc = 0; kc < 4; ++kc) {
            short8v bfrag = *(const short8v*)&wt[(t * 16 + lrow) * XS_STRIDE + kc * 32 + kg * 8];
            acc[t] = __builtin_amdgcn_mfma_f32_16x16x32_bf16(a[kc], bfrag, acc[t], 0, 0, 0);
        }
    }

    // epilogue: scale by dinv, store bf16
    #pragma unroll
    for (int r = 0; r < 4; ++r) {
        int row = row0 + wave * 16 + 4 * kg + r;
        if (row < nrows) {
            float dv = dinv[row];
            #pragma unroll
            for (int t = 0; t < 8; ++t)
                H2s[(size_t)row * DIM + t * 16 + lrow] = bf16r(acc[t][r] * dv);
        }
    }
}

// ---------------- fused gather + residual + bias + LayerNorm + ReLU ---------
// One wave per node; lane owns dims [2*lane, 2*lane+1]. h2 bf16-packed.
// Residual chain is bf16-only: reads xb, writes xb (in-place safe: a node's
// wave reads only its OWN xb row; cross-node reads go through h2 only).
// Edge loop unrolled x2 for memory-level parallelism.

__launch_bounds__(256)
__global__ void gather_ln_kernel(const u32* __restrict__ h2u, const float* __restrict__ dinv,
                                 const int* __restrict__ row_ptr, const int* __restrict__ csr_src,
                                 const float* __restrict__ bl, const float* __restrict__ gamma,
                                 const float* __restrict__ beta, u32* __restrict__ xb) {
    int node = blockIdx.x * 4 + (threadIdx.x >> 6);
    if (node >= NN) return;
    int lane = threadIdx.x & 63;
    int beg = row_ptr[node];
    int end = row_ptr[node + 1];
    int deg = end - beg;

    int myidx = (lane < deg) ? csr_src[beg + lane] : 0;

    u32 sv = h2u[(size_t)node * 64 + lane];  // self-loop term
    float sx = bflo(sv), sy = bfhi(sv);
    float tx = 0.f, ty = 0.f;
    int e = 0;
    for (; e + 2 <= deg; e += 2) {
        int sn0 = (e < 64) ? __shfl(myidx, e) : csr_src[beg + e];
        int sn1 = (e + 1 < 64) ? __shfl(myidx, e + 1) : csr_src[beg + e + 1];
        u32 v0 = h2u[(size_t)sn0 * 64 + lane];
        u32 v1 = h2u[(size_t)sn1 * 64 + lane];
        sx += bflo(v0); sy += bfhi(v0);
        tx += bflo(v1); ty += bfhi(v1);
    }
    if (e < deg) {
        int sn = (e < 64) ? __shfl(myidx, e) : csr_src[beg + e];
        u32 v = h2u[(size_t)sn * 64 + lane];
        sx += bflo(v); sy += bfhi(v);
    }
    sx += tx; sy += ty;

    float dn = dinv[node];
    u32 xv = xb[(size_t)node * 64 + lane];
    float2 bv = ((const float2*)bl)[lane];
    float ax = bflo(xv) + sx * dn + bv.x;
    float ay = bfhi(xv) + sy * dn + bv.y;

    float sum = ax + ay;
    float sq = ax * ax + ay * ay;
    #pragma unroll
    for (int o = 32; o > 0; o >>= 1) {
        sum += __shfl_xor(sum, o);
        sq += __shfl_xor(sq, o);
    }
    float mean = sum * (1.0f / DIM);
    float var = sq * (1.0f / DIM) - mean * mean;
    float rstd = rsqrtf(var + 1e-5f);
    float2 g = ((const float2*)gamma)[lane];
    float2 bt = ((const float2*)beta)[lane];
    float ox = fmaxf((ax - mean) * rstd * g.x + bt.x, 0.f);
    float oy = fmaxf((ay - mean) * rstd * g.y + bt.y, 0.f);
    xb[(size_t)node * 64 + lane] = bf2(ox, oy);
}

// ---------------- global mean pool (batch is SORTED -> segments) ------------

__global__ void bounds_kernel(const int* __restrict__ batch, int* __restrict__ bounds) {
    int g = threadIdx.x;
    if (g > NGRAPH) return;
    int lo = 0, hi = NN;
    while (lo < hi) {
        int mid = (lo + hi) >> 1;
        if (batch[mid] < g) lo = mid + 1; else hi = mid;
    }
    bounds[g] = lo;
}

// stage 1: 4 blocks per graph, each sums a quarter of the segment (bf16 in)
__launch_bounds__(256)
__global__ void pool1_kernel(const u32* __restrict__ xb, const int* __restrict__ bounds,
                             float* __restrict__ partials) {
    __shared__ float part[3][DIM];
    int g = blockIdx.x >> 2;
    int q = blockIdx.x & 3;
    int beg = bounds[g], end = bounds[g + 1];
    int len = end - beg;
    int qbeg = beg + (int)(((long long)len * q) >> 2);
    int qend = beg + (int)(((long long)len * (q + 1)) >> 2);
    int grp = threadIdx.x >> 6;   // 0..3: 4 rows in flight
    int lane = threadIdx.x & 63;  // u32 index within row (2 dims)
    float sx = 0.f, sy = 0.f;
    for (int r = qbeg + grp; r < qend; r += 4) {
        u32 v = xb[(size_t)r * 64 + lane];
        sx += bflo(v);
        sy += bfhi(v);
    }
    if (grp > 0) {
        part[grp - 1][lane * 2 + 0] = sx;
        part[grp - 1][lane * 2 + 1] = sy;
    }
    __syncthreads();
    if (grp == 0) {
        sx += part[0][lane * 2] + part[1][lane * 2] + part[2][lane * 2];
        sy += part[0][lane * 2 + 1] + part[1][lane * 2 + 1] + part[2][lane * 2 + 1];
        partials[(size_t)blockIdx.x * DIM + lane * 2 + 0] = sx;
        partials[(size_t)blockIdx.x * DIM + lane * 2 + 1] = sy;
    }
}

// stage 2: combine 4 partials per graph, divide by count, write out
__launch_bounds__(256)
__global__ void pool2_kernel(const float* __restrict__ partials, const int* __restrict__ bounds,
                             float* __restrict__ out) {
    int t = blockIdx.x * 256 + threadIdx.x;
    if (t >= NGRAPH * DIM) return;
    int g = t >> 7;
    int d = t & 127;
    float s = partials[(size_t)(4 * g + 0) * DIM + d] + partials[(size_t)(4 * g + 1) * DIM + d] +
              partials[(size_t)(4 * g + 2) * DIM + d] + partials[(size_t)(4 * g + 3) * DIM + d];
    float cntf = (float)(bounds[g + 1] - bounds[g]);
    out[t] = s / fmaxf(cntf, 1.0f);
}

// ---------------- launch ----------------------------------------------------

extern "C" void kernel_launch(void* const* d_in, const int* in_sizes, int n_in,
                              void* d_out, int out_size, void* d_ws, size_t ws_size,
                              hipStream_t stream) {
    const float* x     = (const float*)d_in[0];
    const int*   ei    = (const int*)d_in[1];
    const int*   batch = (const int*)d_in[2];
    const float* W     = (const float*)d_in[3];
    const float* b     = (const float*)d_in[4];
    const float* gamma = (const float*)d_in[5];
    const float* beta  = (const float*)d_in[6];
    float* out = (float*)d_out;

    const int* srcE = ei;        // edge_index[0]
    const int* dstE = ei + NE;   // edge_index[1]

    // workspace layout
    char* p = (char*)d_ws;
    u32*   xb      = (u32*)p;    p += (size_t)NN * (DIM / 2) * sizeof(u32);    // 12.8 MB
    unsigned short* h2s = (unsigned short*)p; p += (size_t)NN * DIM * sizeof(unsigned short); // 12.8 MB
    unsigned short* WT  = (unsigned short*)p; p += (size_t)NLAYER * DIM * DIM * sizeof(unsigned short);
    float* dinv    = (float*)p;  p += (size_t)NN * sizeof(float);
    int*   deg     = (int*)p;    p += (size_t)NN * sizeof(int);
    int*   ccnt    = (int*)p;    p += (size_t)NN * sizeof(int);
    int*   row_ptr = (int*)p;    p += (size_t)(NN + 1) * sizeof(int);
    int*   csr_src = (int*)p;    p += (size_t)NE * sizeof(int);
    int*   bounds  = (int*)p;    p += (size_t)(NGRAPH + 1) * sizeof(int);
    int*   bsum    = (int*)p;    p += (size_t)SCAN_BLOCKS * sizeof(int);
    float* partials = (float*)p; p += (size_t)NGRAPH * POOL_SPLIT * DIM * sizeof(float);

    // CSR build
    hipMemsetAsync(deg, 0, NN * sizeof(int), stream);
    hipMemsetAsync(ccnt, 0, NN * sizeof(int), stream);
    deg_kernel<<<(NE + 255) / 256, 256, 0, stream>>>(dstE, deg);
    blocksum_kernel<<<SCAN_BLOCKS, 256, 0, stream>>>(deg, bsum);
    scanb_kernel<<<1, 256, 0, stream>>>(bsum);
    rowptr_kernel<<<SCAN_BLOCKS, 256, 0, stream>>>(deg, bsum, row_ptr, dinv);
    fill_kernel<<<(NE + 255) / 256, 256, 0, stream>>>(srcE, dstE, row_ptr, ccnt, csr_src);
    bounds_kernel<<<1, 256, 0, stream>>>(batch, bounds);

    // one-time conversions
    wprep_kernel<<<(NLAYER * DIM * DIM + 255) / 256, 256, 0, stream>>>(W, WT);
    xconv_kernel<<<(NN * 64 + 255) / 256, 256, 0, stream>>>(x, xb);

    for (int l = 0; l < NLAYER; ++l) {
        gemm_mfma_kernel<<<(NN + 63) / 64, 256, 0, stream>>>(
            xb, WT + (size_t)l * DIM * DIM, dinv, h2s, NN);
        gather_ln_kernel<<<(NN + 3) / 4, 256, 0, stream>>>(
            (const u32*)h2s, dinv, row_ptr, csr_src,
            b + l * DIM, gamma + l * DIM, beta + l * DIM, xb);
    }

    pool1_kernel<<<NGRAPH * POOL_SPLIT, 256, 0, stream>>>(xb, bounds, partials);
    pool2_kernel<<<(NGRAPH * DIM + 255) / 256, 256, 0, stream>>>(partials, bounds, out);
}

// Round 10
// 303.036 us; speedup vs baseline: 15.3142x; 1.0042x over previous
//
#include <hip/hip_runtime.h>

// N=50000 nodes, E=600000 edges, D=128, L=4 layers, G=128 graphs.
#define NN 50000
#define NE 600000
#define DIM 128
#define NLAYER 4
#define NGRAPH 128
#define SCAN_BLOCKS ((NN + 255) / 256)   // 196
#define XS_STRIDE 136                    // bf16 elems per LDS row (128 + 8 pad)
#define POOL_SPLIT 4                     // blocks per graph in pool stage 1

typedef unsigned int u32;
typedef __attribute__((ext_vector_type(8))) short short8v;  // 8 x bf16 (4 VGPR)
typedef __attribute__((ext_vector_type(4))) float f32x4;

// pack two fp32 -> 2x bf16 (round-to-nearest-even)
__device__ __forceinline__ u32 bf2(float a, float b) {
    u32 ua = __float_as_uint(a);
    ua = (ua + 0x7fffu + ((ua >> 16) & 1u)) >> 16;
    u32 ub = __float_as_uint(b);
    ub = (ub + 0x7fffu + ((ub >> 16) & 1u)) >> 16;
    return ua | (ub << 16);
}
__device__ __forceinline__ unsigned short bf16r(float a) {
    u32 u = __float_as_uint(a);
    u = (u + 0x7fffu + ((u >> 16) & 1u)) >> 16;
    return (unsigned short)u;
}
__device__ __forceinline__ float bflo(u32 v) { return __uint_as_float(v << 16); }
__device__ __forceinline__ float bfhi(u32 v) { return __uint_as_float(v & 0xffff0000u); }

// ---------------- CSR build (edge structure only, once per launch) ----------

// zero deg + ccnt in one cheap launch (replaces two slow runtime fills)
__global__ void zero2_kernel(int* __restrict__ a, int* __restrict__ b) {
    int i = blockIdx.x * 256 + threadIdx.x;
    if (i < NN) {
        a[i] = 0;
        b[i] = 0;
    }
}

__global__ void deg_kernel(const int* __restrict__ dst, int* __restrict__ deg) {
    int e = blockIdx.x * blockDim.x + threadIdx.x;
    if (e < NE) atomicAdd(&deg[dst[e]], 1);
}

__launch_bounds__(256)
__global__ void blocksum_kernel(const int* __restrict__ deg, int* __restrict__ bsum) {
    int i = blockIdx.x * 256 + threadIdx.x;
    int v = (i < NN) ? deg[i] : 0;
    #pragma unroll
    for (int o = 32; o > 0; o >>= 1) v += __shfl_xor(v, o);
    __shared__ int ws[4];
    int wid = threadIdx.x >> 6;
    if ((threadIdx.x & 63) == 0) ws[wid] = v;
    __syncthreads();
    if (threadIdx.x == 0) bsum[blockIdx.x] = ws[0] + ws[1] + ws[2] + ws[3];
}

__launch_bounds__(256)
__global__ void scanb_kernel(int* __restrict__ bsum) {
    __shared__ int s[256];
    int tid = threadIdx.x;
    int v = (tid < SCAN_BLOCKS) ? bsum[tid] : 0;
    s[tid] = v;
    __syncthreads();
    for (int o = 1; o < 256; o <<= 1) {
        int t = (tid >= o) ? s[tid - o] : 0;
        __syncthreads();
        s[tid] += t;
        __syncthreads();
    }
    if (tid < SCAN_BLOCKS) bsum[tid] = s[tid] - v;  // exclusive
}

__launch_bounds__(256)
__global__ void rowptr_kernel(const int* __restrict__ deg, const int* __restrict__ bsum,
                              int* __restrict__ row_ptr, float* __restrict__ dinv) {
    __shared__ int s[256];
    int tid = threadIdx.x;
    int i = blockIdx.x * 256 + tid;
    int d = (i < NN) ? deg[i] : 0;
    s[tid] = d;
    __syncthreads();
    for (int o = 1; o < 256; o <<= 1) {
        int t = (tid >= o) ? s[tid - o] : 0;
        __syncthreads();
        s[tid] += t;
        __syncthreads();
    }
    if (i < NN) {
        row_ptr[i] = bsum[blockIdx.x] + s[tid] - d;  // exclusive prefix
        dinv[i] = rsqrtf((float)d + 1.0f);           // +1 self-loop
    }
    if (i == 0) row_ptr[NN] = NE;
}

__global__ void fill_kernel(const int* __restrict__ src, const int* __restrict__ dst,
                            const int* __restrict__ row_ptr, int* __restrict__ cnt,
                            int* __restrict__ csr_src) {
    int e = blockIdx.x * blockDim.x + threadIdx.x;
    if (e >= NE) return;
    int d = dst[e];
    int pos = row_ptr[d] + atomicAdd(&cnt[d], 1);
    csr_src[pos] = src[e];
}

// ---------------- one-time conversions --------------------------------------

// WT[l][n][k] = bf16(W[l][k][n])  (transposed so B-fragments are contiguous)
__global__ void wprep_kernel(const float* __restrict__ W, unsigned short* __restrict__ WT) {
    int t = blockIdx.x * 256 + threadIdx.x;
    if (t >= NLAYER * DIM * DIM) return;
    int l = t >> 14;
    int rem = t & 16383;
    int k = rem >> 7, n = rem & 127;
    WT[(size_t)l * 16384 + n * 128 + k] = bf16r(W[(size_t)l * 16384 + k * 128 + n]);
}

// xb = bf16 packed copy of x
__global__ void xconv_kernel(const float* __restrict__ x, u32* __restrict__ xb) {
    int t = blockIdx.x * 256 + threadIdx.x;
    if (t >= NN * 64) return;
    float2 v = ((const float2*)x)[t];
    xb[t] = bf2(v.x, v.y);
}

// ---------------- GEMM via MFMA: H2[N,128](bf16) = (Xb @ W) * dinv[row] -----
// 256 threads = 4 waves, 64-row tile. X tile + full WT staged in LDS with
// +8 bf16 row padding (row stride 272 B). Rows are 16 uint4 each; LDS row
// stride is 17 uint4. Per wave: 16 rows x 128 cols = 8 (16x16) tiles x
// 4 K-steps of mfma_f32_16x16x32_bf16.
// Layouts (m89-verified): A row=lane&15, k=8*(lane>>4)+j; B col=lane&15,
// same k; D col=lane&15, row=4*(lane>>4)+reg.

__launch_bounds__(256)
__global__ void gemm_mfma_kernel(const u32* __restrict__ Xb, const unsigned short* __restrict__ WTl,
                                 const float* __restrict__ dinv,
                                 unsigned short* __restrict__ H2s, int nrows) {
    __shared__ __align__(16) unsigned short xs[64 * XS_STRIDE];    // 17408 B
    __shared__ __align__(16) unsigned short wt[128 * XS_STRIDE];   // 34816 B
    const int tid = threadIdx.x;
    const int row0 = blockIdx.x * 64;
    const int nr = min(64, nrows - row0);

    // stage X tile: 64 rows x 16 uint4 (zero-fill past nr)
    {
        const uint4* xg = (const uint4*)(Xb + (size_t)row0 * 64);
        uint4* xs4 = (uint4*)xs;
        #pragma unroll
        for (int i = 0; i < 4; ++i) {
            int idx = i * 256 + tid;          // 0..1023
            int r = idx >> 4, c = idx & 15;   // 16 uint4 per row
            uint4 v = make_uint4(0u, 0u, 0u, 0u);
            if (r < nr) v = xg[idx];
            xs4[r * 17 + c] = v;
        }
    }
    // stage WT: 128 rows x 16 uint4
    {
        const uint4* wg = (const uint4*)WTl;
        uint4* wt4 = (uint4*)wt;
        #pragma unroll
        for (int i = 0; i < 8; ++i) {
            int idx = i * 256 + tid;          // 0..2047
            int r = idx >> 4, c = idx & 15;
            wt4[r * 17 + c] = wg[idx];
        }
    }
    __syncthreads();

    const int wave = tid >> 6;
    const int lane = tid & 63;
    const int lrow = lane & 15;   // A row / B col within tile
    const int kg = lane >> 4;     // k-group: k = 32*kc + 8*kg + j

    // A fragments: 4 k-chunks for this wave's 16 rows
    short8v a[4];
    #pragma unroll
    for (int kc = 0; kc < 4; ++kc)
        a[kc] = *(const short8v*)&xs[(wave * 16 + lrow) * XS_STRIDE + kc * 32 + kg * 8];

    f32x4 acc[8];
    #pragma unroll
    for (int t = 0; t < 8; ++t) acc[t] = (f32x4){0.f, 0.f, 0.f, 0.f};

    #pragma unroll
    for (int t = 0; t < 8; ++t) {
        #pragma unroll
        for (int kc = 0; kc < 4; ++kc) {
            short8v bfrag = *(const short8v*)&wt[(t * 16 + lrow) * XS_STRIDE + kc * 32 + kg * 8];
            acc[t] = __builtin_amdgcn_mfma_f32_16x16x32_bf16(a[kc], bfrag, acc[t], 0, 0, 0);
        }
    }

    // epilogue: scale by dinv, store bf16
    #pragma unroll
    for (int r = 0; r < 4; ++r) {
        int row = row0 + wave * 16 + 4 * kg + r;
        if (row < nrows) {
            float dv = dinv[row];
            #pragma unroll
            for (int t = 0; t < 8; ++t)
                H2s[(size_t)row * DIM + t * 16 + lrow] = bf16r(acc[t][r] * dv);
        }
    }
}

// ---------------- fused gather + residual + bias + LayerNorm + ReLU ---------
// One wave per node; lane owns dims [2*lane, 2*lane+1]. h2 bf16-packed.
// Residual chain is bf16-only: reads xb, writes xb (in-place safe: a node's
// wave reads only its OWN xb row; cross-node reads go through h2 only).
// Edge loop unrolled x2 for memory-level parallelism.

__launch_bounds__(256)
__global__ void gather_ln_kernel(const u32* __restrict__ h2u, const float* __restrict__ dinv,
                                 const int* __restrict__ row_ptr, const int* __restrict__ csr_src,
                                 const float* __restrict__ bl, const float* __restrict__ gamma,
                                 const float* __restrict__ beta, u32* __restrict__ xb) {
    int node = blockIdx.x * 4 + (threadIdx.x >> 6);
    if (node >= NN) return;
    int lane = threadIdx.x & 63;
    int beg = row_ptr[node];
    int end = row_ptr[node + 1];
    int deg = end - beg;

    int myidx = (lane < deg) ? csr_src[beg + lane] : 0;

    u32 sv = h2u[(size_t)node * 64 + lane];  // self-loop term
    float sx = bflo(sv), sy = bfhi(sv);
    float tx = 0.f, ty = 0.f;
    int e = 0;
    for (; e + 2 <= deg; e += 2) {
        int sn0 = (e < 64) ? __shfl(myidx, e) : csr_src[beg + e];
        int sn1 = (e + 1 < 64) ? __shfl(myidx, e + 1) : csr_src[beg + e + 1];
        u32 v0 = h2u[(size_t)sn0 * 64 + lane];
        u32 v1 = h2u[(size_t)sn1 * 64 + lane];
        sx += bflo(v0); sy += bfhi(v0);
        tx += bflo(v1); ty += bfhi(v1);
    }
    if (e < deg) {
        int sn = (e < 64) ? __shfl(myidx, e) : csr_src[beg + e];
        u32 v = h2u[(size_t)sn * 64 + lane];
        sx += bflo(v); sy += bfhi(v);
    }
    sx += tx; sy += ty;

    float dn = dinv[node];
    u32 xv = xb[(size_t)node * 64 + lane];
    float2 bv = ((const float2*)bl)[lane];
    float ax = bflo(xv) + sx * dn + bv.x;
    float ay = bfhi(xv) + sy * dn + bv.y;

    float sum = ax + ay;
    float sq = ax * ax + ay * ay;
    #pragma unroll
    for (int o = 32; o > 0; o >>= 1) {
        sum += __shfl_xor(sum, o);
        sq += __shfl_xor(sq, o);
    }
    float mean = sum * (1.0f / DIM);
    float var = sq * (1.0f / DIM) - mean * mean;
    float rstd = rsqrtf(var + 1e-5f);
    float2 g = ((const float2*)gamma)[lane];
    float2 bt = ((const float2*)beta)[lane];
    float ox = fmaxf((ax - mean) * rstd * g.x + bt.x, 0.f);
    float oy = fmaxf((ay - mean) * rstd * g.y + bt.y, 0.f);
    xb[(size_t)node * 64 + lane] = bf2(ox, oy);
}

// ---------------- global mean pool (batch is SORTED -> segments) ------------

__global__ void bounds_kernel(const int* __restrict__ batch, int* __restrict__ bounds) {
    int g = threadIdx.x;
    if (g > NGRAPH) return;
    int lo = 0, hi = NN;
    while (lo < hi) {
        int mid = (lo + hi) >> 1;
        if (batch[mid] < g) lo = mid + 1; else hi = mid;
    }
    bounds[g] = lo;
}

// stage 1: 4 blocks per graph, each sums a quarter of the segment (bf16 in)
__launch_bounds__(256)
__global__ void pool1_kernel(const u32* __restrict__ xb, const int* __restrict__ bounds,
                             float* __restrict__ partials) {
    __shared__ float part[3][DIM];
    int g = blockIdx.x >> 2;
    int q = blockIdx.x & 3;
    int beg = bounds[g], end = bounds[g + 1];
    int len = end - beg;
    int qbeg = beg + (int)(((long long)len * q) >> 2);
    int qend = beg + (int)(((long long)len * (q + 1)) >> 2);
    int grp = threadIdx.x >> 6;   // 0..3: 4 rows in flight
    int lane = threadIdx.x & 63;  // u32 index within row (2 dims)
    float sx = 0.f, sy = 0.f;
    for (int r = qbeg + grp; r < qend; r += 4) {
        u32 v = xb[(size_t)r * 64 + lane];
        sx += bflo(v);
        sy += bfhi(v);
    }
    if (grp > 0) {
        part[grp - 1][lane * 2 + 0] = sx;
        part[grp - 1][lane * 2 + 1] = sy;
    }
    __syncthreads();
    if (grp == 0) {
        sx += part[0][lane * 2] + part[1][lane * 2] + part[2][lane * 2];
        sy += part[0][lane * 2 + 1] + part[1][lane * 2 + 1] + part[2][lane * 2 + 1];
        partials[(size_t)blockIdx.x * DIM + lane * 2 + 0] = sx;
        partials[(size_t)blockIdx.x * DIM + lane * 2 + 1] = sy;
    }
}

// stage 2: combine 4 partials per graph, divide by count, write out
__launch_bounds__(256)
__global__ void pool2_kernel(const float* __restrict__ partials, const int* __restrict__ bounds,
                             float* __restrict__ out) {
    int t = blockIdx.x * 256 + threadIdx.x;
    if (t >= NGRAPH * DIM) return;
    int g = t >> 7;
    int d = t & 127;
    float s = partials[(size_t)(4 * g + 0) * DIM + d] + partials[(size_t)(4 * g + 1) * DIM + d] +
              partials[(size_t)(4 * g + 2) * DIM + d] + partials[(size_t)(4 * g + 3) * DIM + d];
    float cntf = (float)(bounds[g + 1] - bounds[g]);
    out[t] = s / fmaxf(cntf, 1.0f);
}

// ---------------- launch ----------------------------------------------------

extern "C" void kernel_launch(void* const* d_in, const int* in_sizes, int n_in,
                              void* d_out, int out_size, void* d_ws, size_t ws_size,
                              hipStream_t stream) {
    const float* x     = (const float*)d_in[0];
    const int*   ei    = (const int*)d_in[1];
    const int*   batch = (const int*)d_in[2];
    const float* W     = (const float*)d_in[3];
    const float* b     = (const float*)d_in[4];
    const float* gamma = (const float*)d_in[5];
    const float* beta  = (const float*)d_in[6];
    float* out = (float*)d_out;

    const int* srcE = ei;        // edge_index[0]
    const int* dstE = ei + NE;   // edge_index[1]

    // workspace layout
    char* p = (char*)d_ws;
    u32*   xb      = (u32*)p;    p += (size_t)NN * (DIM / 2) * sizeof(u32);    // 12.8 MB
    unsigned short* h2s = (unsigned short*)p; p += (size_t)NN * DIM * sizeof(unsigned short); // 12.8 MB
    unsigned short* WT  = (unsigned short*)p; p += (size_t)NLAYER * DIM * DIM * sizeof(unsigned short);
    float* dinv    = (float*)p;  p += (size_t)NN * sizeof(float);
    int*   deg     = (int*)p;    p += (size_t)NN * sizeof(int);
    int*   ccnt    = (int*)p;    p += (size_t)NN * sizeof(int);
    int*   row_ptr = (int*)p;    p += (size_t)(NN + 1) * sizeof(int);
    int*   csr_src = (int*)p;    p += (size_t)NE * sizeof(int);
    int*   bounds  = (int*)p;    p += (size_t)(NGRAPH + 1) * sizeof(int);
    int*   bsum    = (int*)p;    p += (size_t)SCAN_BLOCKS * sizeof(int);
    float* partials = (float*)p; p += (size_t)NGRAPH * POOL_SPLIT * DIM * sizeof(float);

    // CSR build (zero via custom kernel — runtime fillBuffer was 43 µs each)
    zero2_kernel<<<SCAN_BLOCKS, 256, 0, stream>>>(deg, ccnt);
    deg_kernel<<<(NE + 255) / 256, 256, 0, stream>>>(dstE, deg);
    blocksum_kernel<<<SCAN_BLOCKS, 256, 0, stream>>>(deg, bsum);
    scanb_kernel<<<1, 256, 0, stream>>>(bsum);
    rowptr_kernel<<<SCAN_BLOCKS, 256, 0, stream>>>(deg, bsum, row_ptr, dinv);
    fill_kernel<<<(NE + 255) / 256, 256, 0, stream>>>(srcE, dstE, row_ptr, ccnt, csr_src);
    bounds_kernel<<<1, 256, 0, stream>>>(batch, bounds);

    // one-time conversions
    wprep_kernel<<<(NLAYER * DIM * DIM + 255) / 256, 256, 0, stream>>>(W, WT);
    xconv_kernel<<<(NN * 64 + 255) / 256, 256, 0, stream>>>(x, xb);

    for (int l = 0; l < NLAYER; ++l) {
        gemm_mfma_kernel<<<(NN + 63) / 64, 256, 0, stream>>>(
            xb, WT + (size_t)l * DIM * DIM, dinv, h2s, NN);
        gather_ln_kernel<<<(NN + 3) / 4, 256, 0, stream>>>(
            (const u32*)h2s, dinv, row_ptr, csr_src,
            b + l * DIM, gamma + l * DIM, beta + l * DIM, xb);
    }

    pool1_kernel<<<NGRAPH * POOL_SPLIT, 256, 0, stream>>>(xb, bounds, partials);
    pool2_kernel<<<(NGRAPH * DIM + 255) / 256, 256, 0, stream>>>(partials, bounds, out);
}

// Round 11
// 264.559 us; speedup vs baseline: 17.5415x; 1.1454x over previous
//
#include <hip/hip_runtime.h>

// N=50000 nodes, E=600000 edges, D=128, L=4 layers, G=128 graphs.
#define NN 50000
#define NE 600000
#define DIM 128
#define NLAYER 4
#define NGRAPH 128
#define SCAN_BLOCKS ((NN + 255) / 256)   // 196
#define XS_STRIDE 136                    // bf16 elems per LDS row (128 + 8 pad)
#define POOL_SPLIT 4                     // blocks per graph in pool stage 1

typedef unsigned int u32;
typedef __attribute__((ext_vector_type(8))) short short8v;  // 8 x bf16 (4 VGPR)
typedef __attribute__((ext_vector_type(4))) float f32x4;

// pack two fp32 -> 2x bf16 (round-to-nearest-even)
__device__ __forceinline__ u32 bf2(float a, float b) {
    u32 ua = __float_as_uint(a);
    ua = (ua + 0x7fffu + ((ua >> 16) & 1u)) >> 16;
    u32 ub = __float_as_uint(b);
    ub = (ub + 0x7fffu + ((ub >> 16) & 1u)) >> 16;
    return ua | (ub << 16);
}
__device__ __forceinline__ unsigned short bf16r(float a) {
    u32 u = __float_as_uint(a);
    u = (u + 0x7fffu + ((u >> 16) & 1u)) >> 16;
    return (unsigned short)u;
}
__device__ __forceinline__ float bflo(u32 v) { return __uint_as_float(v << 16); }
__device__ __forceinline__ float bfhi(u32 v) { return __uint_as_float(v & 0xffff0000u); }

// ---------------- CSR build (edge structure only, once per launch) ----------

__global__ void zero2_kernel(int* __restrict__ a, int* __restrict__ b) {
    int i = blockIdx.x * 256 + threadIdx.x;
    if (i < NN) {
        a[i] = 0;
        b[i] = 0;
    }
}

__global__ void deg_kernel(const int* __restrict__ dst, int* __restrict__ deg) {
    int e = blockIdx.x * blockDim.x + threadIdx.x;
    if (e < NE) atomicAdd(&deg[dst[e]], 1);
}

__launch_bounds__(256)
__global__ void blocksum_kernel(const int* __restrict__ deg, int* __restrict__ bsum) {
    int i = blockIdx.x * 256 + threadIdx.x;
    int v = (i < NN) ? deg[i] : 0;
    #pragma unroll
    for (int o = 32; o > 0; o >>= 1) v += __shfl_xor(v, o);
    __shared__ int ws[4];
    int wid = threadIdx.x >> 6;
    if ((threadIdx.x & 63) == 0) ws[wid] = v;
    __syncthreads();
    if (threadIdx.x == 0) bsum[blockIdx.x] = ws[0] + ws[1] + ws[2] + ws[3];
}

__launch_bounds__(256)
__global__ void scanb_kernel(int* __restrict__ bsum) {
    __shared__ int s[256];
    int tid = threadIdx.x;
    int v = (tid < SCAN_BLOCKS) ? bsum[tid] : 0;
    s[tid] = v;
    __syncthreads();
    for (int o = 1; o < 256; o <<= 1) {
        int t = (tid >= o) ? s[tid - o] : 0;
        __syncthreads();
        s[tid] += t;
        __syncthreads();
    }
    if (tid < SCAN_BLOCKS) bsum[tid] = s[tid] - v;  // exclusive
}

__launch_bounds__(256)
__global__ void rowptr_kernel(const int* __restrict__ deg, const int* __restrict__ bsum,
                              int* __restrict__ row_ptr, float* __restrict__ dinv) {
    __shared__ int s[256];
    int tid = threadIdx.x;
    int i = blockIdx.x * 256 + tid;
    int d = (i < NN) ? deg[i] : 0;
    s[tid] = d;
    __syncthreads();
    for (int o = 1; o < 256; o <<= 1) {
        int t = (tid >= o) ? s[tid - o] : 0;
        __syncthreads();
        s[tid] += t;
        __syncthreads();
    }
    if (i < NN) {
        row_ptr[i] = bsum[blockIdx.x] + s[tid] - d;  // exclusive prefix
        dinv[i] = rsqrtf((float)d + 1.0f);           // +1 self-loop
    }
    if (i == 0) row_ptr[NN] = NE;
}

__global__ void fill_kernel(const int* __restrict__ src, const int* __restrict__ dst,
                            const int* __restrict__ row_ptr, int* __restrict__ cnt,
                            int* __restrict__ csr_src) {
    int e = blockIdx.x * blockDim.x + threadIdx.x;
    if (e >= NE) return;
    int d = dst[e];
    int pos = row_ptr[d] + atomicAdd(&cnt[d], 1);
    csr_src[pos] = src[e];
}

// ---------------- one-time conversions (fused) -------------------------------
// t < NN*64: xb = bf16 packed x. Else: WT[l][n][k] = bf16(W[l][k][n]).

__global__ void conv_kernel(const float* __restrict__ x, u32* __restrict__ xb,
                            const float* __restrict__ W, unsigned short* __restrict__ WT) {
    int t = blockIdx.x * 256 + threadIdx.x;
    if (t < NN * 64) {
        float2 v = ((const float2*)x)[t];
        xb[t] = bf2(v.x, v.y);
    } else {
        t -= NN * 64;
        if (t < NLAYER * DIM * DIM) {
            int l = t >> 14;
            int rem = t & 16383;
            int k = rem >> 7, n = rem & 127;
            WT[(size_t)l * 16384 + n * 128 + k] = bf16r(W[(size_t)l * 16384 + k * 128 + n]);
        }
    }
}

// ---------------- GEMM via MFMA: H2[N,128](bf16) = (Xb @ W) * dinv[row] -----
// 256 threads = 4 waves, 64-row tile. X tile + full WT staged in LDS with
// +8 bf16 row padding. Rows are 16 uint4; LDS row stride 17 uint4.
// Layouts (m89-verified): A row=lane&15, k=8*(lane>>4)+j; B col=lane&15,
// same k; D col=lane&15, row=4*(lane>>4)+reg.

__launch_bounds__(256)
__global__ void gemm_mfma_kernel(const u32* __restrict__ Xb, const unsigned short* __restrict__ WTl,
                                 const float* __restrict__ dinv,
                                 unsigned short* __restrict__ H2s, int nrows) {
    __shared__ __align__(16) unsigned short xs[64 * XS_STRIDE];    // 17408 B
    __shared__ __align__(16) unsigned short wt[128 * XS_STRIDE];   // 34816 B
    const int tid = threadIdx.x;
    const int row0 = blockIdx.x * 64;
    const int nr = min(64, nrows - row0);

    {
        const uint4* xg = (const uint4*)(Xb + (size_t)row0 * 64);
        uint4* xs4 = (uint4*)xs;
        #pragma unroll
        for (int i = 0; i < 4; ++i) {
            int idx = i * 256 + tid;          // 0..1023
            int r = idx >> 4, c = idx & 15;   // 16 uint4 per row
            uint4 v = make_uint4(0u, 0u, 0u, 0u);
            if (r < nr) v = xg[idx];
            xs4[r * 17 + c] = v;
        }
    }
    {
        const uint4* wg = (const uint4*)WTl;
        uint4* wt4 = (uint4*)wt;
        #pragma unroll
        for (int i = 0; i < 8; ++i) {
            int idx = i * 256 + tid;          // 0..2047
            int r = idx >> 4, c = idx & 15;
            wt4[r * 17 + c] = wg[idx];
        }
    }
    __syncthreads();

    const int wave = tid >> 6;
    const int lane = tid & 63;
    const int lrow = lane & 15;
    const int kg = lane >> 4;

    short8v a[4];
    #pragma unroll
    for (int kc = 0; kc < 4; ++kc)
        a[kc] = *(const short8v*)&xs[(wave * 16 + lrow) * XS_STRIDE + kc * 32 + kg * 8];

    f32x4 acc[8];
    #pragma unroll
    for (int t = 0; t < 8; ++t) acc[t] = (f32x4){0.f, 0.f, 0.f, 0.f};

    #pragma unroll
    for (int t = 0; t < 8; ++t) {
        #pragma unroll
        for (int kc = 0; kc < 4; ++kc) {
            short8v bfrag = *(const short8v*)&wt[(t * 16 + lrow) * XS_STRIDE + kc * 32 + kg * 8];
            acc[t] = __builtin_amdgcn_mfma_f32_16x16x32_bf16(a[kc], bfrag, acc[t], 0, 0, 0);
        }
    }

    #pragma unroll
    for (int r = 0; r < 4; ++r) {
        int row = row0 + wave * 16 + 4 * kg + r;
        if (row < nrows) {
            float dv = dinv[row];
            #pragma unroll
            for (int t = 0; t < 8; ++t)
                H2s[(size_t)row * DIM + t * 16 + lrow] = bf16r(acc[t][r] * dv);
        }
    }
}

// ---------------- fused gather + residual + bias + LayerNorm + ReLU ---------
// TWO nodes per wave (32-lane halves); lane owns 4 dims via uint2 (8B) loads.
// Edge loop unrolled x4 -> up to 8 rows in flight per wave (MLP).
// LN reduce via width-32 shuffles. NN = 6250 blocks * 8 nodes exactly.

__launch_bounds__(256)
__global__ void gather_ln_kernel(const u32* __restrict__ h2u, const float* __restrict__ dinv,
                                 const int* __restrict__ row_ptr, const int* __restrict__ csr_src,
                                 const float* __restrict__ bl, const float* __restrict__ gamma,
                                 const float* __restrict__ beta, u32* __restrict__ xb) {
    int node = blockIdx.x * 8 + (threadIdx.x >> 5);
    int l = threadIdx.x & 31;
    int beg = row_ptr[node];
    int deg = row_ptr[node + 1] - beg;

    // preload up to 32 neighbor indices, one per lane of this half-wave
    int myidx = (l < deg) ? csr_src[beg + l] : 0;

    uint2 sv = ((const uint2*)(h2u + (size_t)node * 64))[l];  // self-loop term
    float a0 = bflo(sv.x), a1 = bfhi(sv.x), a2 = bflo(sv.y), a3 = bfhi(sv.y);
    float c0 = 0.f, c1 = 0.f, c2 = 0.f, c3 = 0.f;

    int e = 0;
    for (; e + 4 <= deg; e += 4) {
        int sn0 = (e     < 32) ? __shfl(myidx, e,     32) : csr_src[beg + e];
        int sn1 = (e + 1 < 32) ? __shfl(myidx, e + 1, 32) : csr_src[beg + e + 1];
        int sn2 = (e + 2 < 32) ? __shfl(myidx, e + 2, 32) : csr_src[beg + e + 2];
        int sn3 = (e + 3 < 32) ? __shfl(myidx, e + 3, 32) : csr_src[beg + e + 3];
        uint2 v0 = ((const uint2*)(h2u + (size_t)sn0 * 64))[l];
        uint2 v1 = ((const uint2*)(h2u + (size_t)sn1 * 64))[l];
        uint2 v2 = ((const uint2*)(h2u + (size_t)sn2 * 64))[l];
        uint2 v3 = ((const uint2*)(h2u + (size_t)sn3 * 64))[l];
        a0 += bflo(v0.x); a1 += bfhi(v0.x); a2 += bflo(v0.y); a3 += bfhi(v0.y);
        c0 += bflo(v1.x); c1 += bfhi(v1.x); c2 += bflo(v1.y); c3 += bfhi(v1.y);
        a0 += bflo(v2.x); a1 += bfhi(v2.x); a2 += bflo(v2.y); a3 += bfhi(v2.y);
        c0 += bflo(v3.x); c1 += bfhi(v3.x); c2 += bflo(v3.y); c3 += bfhi(v3.y);
    }
    for (; e < deg; ++e) {
        int sn = (e < 32) ? __shfl(myidx, e, 32) : csr_src[beg + e];
        uint2 v = ((const uint2*)(h2u + (size_t)sn * 64))[l];
        a0 += bflo(v.x); a1 += bfhi(v.x); a2 += bflo(v.y); a3 += bfhi(v.y);
    }
    a0 += c0; a1 += c1; a2 += c2; a3 += c3;

    float dn = dinv[node];
    uint2 xv = ((const uint2*)(xb + (size_t)node * 64))[l];
    float4 bv = ((const float4*)bl)[l];
    float ax = bflo(xv.x) + a0 * dn + bv.x;
    float ay = bfhi(xv.x) + a1 * dn + bv.y;
    float az = bflo(xv.y) + a2 * dn + bv.z;
    float aw = bfhi(xv.y) + a3 * dn + bv.w;

    float sum = ax + ay + az + aw;
    float sq = ax * ax + ay * ay + az * az + aw * aw;
    #pragma unroll
    for (int o = 16; o > 0; o >>= 1) {
        sum += __shfl_xor(sum, o, 32);
        sq += __shfl_xor(sq, o, 32);
    }
    float mean = sum * (1.0f / DIM);
    float var = sq * (1.0f / DIM) - mean * mean;
    float rstd = rsqrtf(var + 1e-5f);
    float4 g = ((const float4*)gamma)[l];
    float4 bt = ((const float4*)beta)[l];
    float ox = fmaxf((ax - mean) * rstd * g.x + bt.x, 0.f);
    float oy = fmaxf((ay - mean) * rstd * g.y + bt.y, 0.f);
    float oz = fmaxf((az - mean) * rstd * g.z + bt.z, 0.f);
    float ow = fmaxf((aw - mean) * rstd * g.w + bt.w, 0.f);
    uint2 o;
    o.x = bf2(ox, oy);
    o.y = bf2(oz, ow);
    ((uint2*)(xb + (size_t)node * 64))[l] = o;
}

// ---------------- global mean pool (batch is SORTED -> segments) ------------

__global__ void bounds_kernel(const int* __restrict__ batch, int* __restrict__ bounds) {
    int g = threadIdx.x;
    if (g > NGRAPH) return;
    int lo = 0, hi = NN;
    while (lo < hi) {
        int mid = (lo + hi) >> 1;
        if (batch[mid] < g) lo = mid + 1; else hi = mid;
    }
    bounds[g] = lo;
}

__launch_bounds__(256)
__global__ void pool1_kernel(const u32* __restrict__ xb, const int* __restrict__ bounds,
                             float* __restrict__ partials) {
    __shared__ float part[3][DIM];
    int g = blockIdx.x >> 2;
    int q = blockIdx.x & 3;
    int beg = bounds[g], end = bounds[g + 1];
    int len = end - beg;
    int qbeg = beg + (int)(((long long)len * q) >> 2);
    int qend = beg + (int)(((long long)len * (q + 1)) >> 2);
    int grp = threadIdx.x >> 6;
    int lane = threadIdx.x & 63;
    float sx = 0.f, sy = 0.f;
    for (int r = qbeg + grp; r < qend; r += 4) {
        u32 v = xb[(size_t)r * 64 + lane];
        sx += bflo(v);
        sy += bfhi(v);
    }
    if (grp > 0) {
        part[grp - 1][lane * 2 + 0] = sx;
        part[grp - 1][lane * 2 + 1] = sy;
    }
    __syncthreads();
    if (grp == 0) {
        sx += part[0][lane * 2] + part[1][lane * 2] + part[2][lane * 2];
        sy += part[0][lane * 2 + 1] + part[1][lane * 2 + 1] + part[2][lane * 2 + 1];
        partials[(size_t)blockIdx.x * DIM + lane * 2 + 0] = sx;
        partials[(size_t)blockIdx.x * DIM + lane * 2 + 1] = sy;
    }
}

__launch_bounds__(256)
__global__ void pool2_kernel(const float* __restrict__ partials, const int* __restrict__ bounds,
                             float* __restrict__ out) {
    int t = blockIdx.x * 256 + threadIdx.x;
    if (t >= NGRAPH * DIM) return;
    int g = t >> 7;
    int d = t & 127;
    float s = partials[(size_t)(4 * g + 0) * DIM + d] + partials[(size_t)(4 * g + 1) * DIM + d] +
              partials[(size_t)(4 * g + 2) * DIM + d] + partials[(size_t)(4 * g + 3) * DIM + d];
    float cntf = (float)(bounds[g + 1] - bounds[g]);
    out[t] = s / fmaxf(cntf, 1.0f);
}

// ---------------- launch ----------------------------------------------------

extern "C" void kernel_launch(void* const* d_in, const int* in_sizes, int n_in,
                              void* d_out, int out_size, void* d_ws, size_t ws_size,
                              hipStream_t stream) {
    const float* x     = (const float*)d_in[0];
    const int*   ei    = (const int*)d_in[1];
    const int*   batch = (const int*)d_in[2];
    const float* W     = (const float*)d_in[3];
    const float* b     = (const float*)d_in[4];
    const float* gamma = (const float*)d_in[5];
    const float* beta  = (const float*)d_in[6];
    float* out = (float*)d_out;

    const int* srcE = ei;        // edge_index[0]
    const int* dstE = ei + NE;   // edge_index[1]

    // workspace layout
    char* p = (char*)d_ws;
    u32*   xb      = (u32*)p;    p += (size_t)NN * (DIM / 2) * sizeof(u32);    // 12.8 MB
    unsigned short* h2s = (unsigned short*)p; p += (size_t)NN * DIM * sizeof(unsigned short); // 12.8 MB
    unsigned short* WT  = (unsigned short*)p; p += (size_t)NLAYER * DIM * DIM * sizeof(unsigned short);
    float* dinv    = (float*)p;  p += (size_t)NN * sizeof(float);
    int*   deg     = (int*)p;    p += (size_t)NN * sizeof(int);
    int*   ccnt    = (int*)p;    p += (size_t)NN * sizeof(int);
    int*   row_ptr = (int*)p;    p += (size_t)(NN + 1) * sizeof(int);
    int*   csr_src = (int*)p;    p += (size_t)NE * sizeof(int);
    int*   bounds  = (int*)p;    p += (size_t)(NGRAPH + 1) * sizeof(int);
    int*   bsum    = (int*)p;    p += (size_t)SCAN_BLOCKS * sizeof(int);
    float* partials = (float*)p; p += (size_t)NGRAPH * POOL_SPLIT * DIM * sizeof(float);

    // CSR build
    zero2_kernel<<<SCAN_BLOCKS, 256, 0, stream>>>(deg, ccnt);
    deg_kernel<<<(NE + 255) / 256, 256, 0, stream>>>(dstE, deg);
    blocksum_kernel<<<SCAN_BLOCKS, 256, 0, stream>>>(deg, bsum);
    scanb_kernel<<<1, 256, 0, stream>>>(bsum);
    rowptr_kernel<<<SCAN_BLOCKS, 256, 0, stream>>>(deg, bsum, row_ptr, dinv);
    fill_kernel<<<(NE + 255) / 256, 256, 0, stream>>>(srcE, dstE, row_ptr, ccnt, csr_src);
    bounds_kernel<<<1, 256, 0, stream>>>(batch, bounds);

    // one-time conversions (fused)
    conv_kernel<<<(NN * 64 + NLAYER * DIM * DIM + 255) / 256, 256, 0, stream>>>(x, xb, W, WT);

    for (int l = 0; l < NLAYER; ++l) {
        gemm_mfma_kernel<<<(NN + 63) / 64, 256, 0, stream>>>(
            xb, WT + (size_t)l * DIM * DIM, dinv, h2s, NN);
        gather_ln_kernel<<<NN / 8, 256, 0, stream>>>(
            (const u32*)h2s, dinv, row_ptr, csr_src,
            b + l * DIM, gamma + l * DIM, beta + l * DIM, xb);
    }

    pool1_kernel<<<NGRAPH * POOL_SPLIT, 256, 0, stream>>>(xb, bounds, partials);
    pool2_kernel<<<(NGRAPH * DIM + 255) / 256, 256, 0, stream>>>(partials, bounds, out);
}